// Round 1
// baseline (308.096 us; speedup 1.0000x reference)
//
#include <hip/hip_runtime.h>
#include <hip/hip_bf16.h>

typedef __attribute__((ext_vector_type(8))) short short8;
typedef __attribute__((ext_vector_type(4))) float floatx4;

#define L_SEQ 2048
#define EMB   1024
#define HD    64
#define QSCALE 0.18033688011112042f   /* 0.125 * log2(e) */
#define FIXMAX2 11.541560327111707f   /* 8 * log2(e) */

__device__ __forceinline__ unsigned short f2bf(float f) {
    unsigned int u = __float_as_uint(f);
    u += 0x7fffu + ((u >> 16) & 1u);   // RNE
    return (unsigned short)(u >> 16);
}
__device__ __forceinline__ unsigned pkbf(float a, float b) {
    return (unsigned)f2bf(a) | ((unsigned)f2bf(b) << 16);
}
__device__ __forceinline__ unsigned pkbf2(float a, float b) {
    __hip_bfloat162 h = __float22bfloat162_rn(make_float2(a, b));
    unsigned u; __builtin_memcpy(&u, &h, 4); return u;
}
__device__ __forceinline__ void gld_lds16(const void* g, void* l) {
    __builtin_amdgcn_global_load_lds(
        (const __attribute__((address_space(1))) unsigned*)g,
        (__attribute__((address_space(3))) unsigned*)l, 16, 0, 0);
}
__device__ __forceinline__ float fexp2(float x) {
    return __builtin_amdgcn_exp2f(x);   // v_exp_f32 (2^x)
}

// ---------- Kernel 0: convert weights + activations fp32 -> bf16 ----------
__global__ __launch_bounds__(256) void convert_all(
    const float* __restrict__ q, const float* __restrict__ k,
    const float* __restrict__ v, const float* __restrict__ ipw,
    const float* __restrict__ opw,
    unsigned short* __restrict__ Abq, unsigned short* __restrict__ Abk,
    unsigned short* __restrict__ Abv, unsigned short* __restrict__ Wipb,
    unsigned short* __restrict__ Wopb)
{
    const int NA = 1048576, NIP = 786432;        // float4 units
    int idx = blockIdx.x * 256 + threadIdx.x;    // 0 .. 4194303
    const float* src; unsigned short* dst; int o;
    if (idx < NA)            { src = q;   dst = Abq;  o = idx; }
    else if (idx < 2 * NA)   { src = k;   dst = Abk;  o = idx - NA; }
    else if (idx < 3 * NA)   { src = v;   dst = Abv;  o = idx - 2 * NA; }
    else if (idx < 3 * NA + NIP) { src = ipw; dst = Wipb; o = idx - 3 * NA; }
    else                     { src = opw; dst = Wopb; o = idx - 3 * NA - NIP; }
    float4 f = ((const float4*)src)[o];
    ((uint2*)dst)[o] = make_uint2(pkbf(f.x, f.y), pkbf(f.z, f.w));
}

// ---------- Kernel 1: QKV projection, all-bf16 (N=3072) ----------
__global__ __launch_bounds__(256, 3) void qkv_gemm(
    const unsigned short* __restrict__ Abq, const unsigned short* __restrict__ Abk,
    const unsigned short* __restrict__ Abv, const unsigned short* __restrict__ Wb,
    const float* __restrict__ Bip,
    unsigned short* __restrict__ Qh, unsigned short* __restrict__ Kh,
    unsigned short* __restrict__ Vt)
{
    __shared__ unsigned short lds[17408];
    unsigned short* As = lds;
    unsigned short* Bs = lds + 8192;

    const int tid = threadIdx.x, lane = tid & 63, w = tid >> 6;
    const int wm = (w & 1) * 64, wn = (w >> 1) * 64;
    const int m0 = blockIdx.x * 128, n0 = blockIdx.y * 128;
    const int cn = lane & 15, g = lane >> 4;
    const int z = n0 >> 10;
    const unsigned short* Ag = (z == 0) ? Abq : (z == 1) ? Abk : Abv;

    floatx4 acc[4][4];
    #pragma unroll
    for (int i = 0; i < 4; ++i)
        #pragma unroll
        for (int j = 0; j < 4; ++j) acc[i][j] = (floatx4){0.f, 0.f, 0.f, 0.f};

    for (int k0 = 0; k0 < EMB; k0 += 64) {
        __syncthreads();
        #pragma unroll
        for (int p = 0; p < 4; ++p) {
            int u0 = (p * 4 + w) * 64, u = u0 + lane, row = u >> 3, sl = u & 7;
            gld_lds16(Ag + (size_t)(m0 + row) * EMB + k0 + ((sl ^ (row & 7)) * 8), &As[u0 * 8]);
            gld_lds16(Wb + (size_t)(n0 + row) * EMB + k0 + ((sl ^ (row & 7)) * 8), &Bs[u0 * 8]);
        }
        __syncthreads();
        #pragma unroll
        for (int kc = 0; kc < 2; ++kc) {
            short8 a4[4], b4[4];
            #pragma unroll
            for (int i = 0; i < 4; ++i)
                a4[i] = *(const short8*)&As[(wm + i * 16 + cn) * 64 + (((kc * 4 + g) ^ (cn & 7)) * 8)];
            #pragma unroll
            for (int j = 0; j < 4; ++j)
                b4[j] = *(const short8*)&Bs[(wn + j * 16 + cn) * 64 + (((kc * 4 + g) ^ (cn & 7)) * 8)];
            #pragma unroll
            for (int i = 0; i < 4; ++i)
                #pragma unroll
                for (int j = 0; j < 4; ++j)
                    acc[i][j] = __builtin_amdgcn_mfma_f32_16x16x32_bf16(a4[i], b4[j], acc[i][j], 0, 0, 0);
        }
    }

    if (z < 2) {
        #pragma unroll
        for (int j = 0; j < 4; ++j) {
            int col = n0 + wn + j * 16 + cn;
            float bv = Bip[col];
            int o = col & 1023, h = o >> 6, d = o & 63;
            #pragma unroll
            for (int i = 0; i < 4; ++i)
                #pragma unroll
                for (int r = 0; r < 4; ++r) {
                    int rr = m0 + wm + i * 16 + g * 4 + r;   // l*2 + b
                    float vv = acc[i][j][r] + bv;
                    int l = rr >> 1, bb = rr & 1, nn = bb * 16 + h;
                    if (z == 0) Qh[((size_t)nn * L_SEQ + l) * HD + d] = f2bf(vv * QSCALE);
                    else        Kh[((size_t)nn * L_SEQ + l) * HD + d] = f2bf(vv);
                }
        }
    } else {
        // z==2: LDS-transposed epilogue -> Vt[n][d][l] coalesced 16B stores
        __syncthreads();
        #pragma unroll
        for (int j = 0; j < 4; ++j) {
            int col_l = wn + j * 16 + cn;
            float bv = Bip[n0 + col_l];
            #pragma unroll
            for (int i = 0; i < 4; ++i) {
                int rrb = wm + i * 16 + g * 4;
                int l0 = rrb >> 1;
                float v0 = acc[i][j][0] + bv, v1 = acc[i][j][1] + bv;
                float v2 = acc[i][j][2] + bv, v3 = acc[i][j][3] + bv;
                *(unsigned*)&lds[col_l * 136 +      l0] = pkbf(v0, v2);
                *(unsigned*)&lds[col_l * 136 + 64 + l0] = pkbf(v1, v3);
            }
        }
        __syncthreads();
        int cl = tid >> 1, bb = tid & 1;
        int o = (n0 - 2048) + cl, h = o >> 6, d = o & 63;
        int nn = bb * 16 + h;
        unsigned short* dst = Vt + ((size_t)nn * HD + d) * L_SEQ + (m0 >> 1);
        const unsigned short* srcp = &lds[cl * 136 + bb * 64];
        #pragma unroll
        for (int i = 0; i < 8; ++i)
            *(uint4*)(dst + i * 8) = *(const uint4*)(srcp + i * 8);
    }
}

// ---------- Kernel 1b: repack K,V into MFMA-fragment-contiguous chunks ------
// Kf chunk ck=(n*128+kt)*2+kc : lane g*16+cn holds Kh[n][kt*16+cn][kc*32+g*8 ..+7]
// Vf chunk cv=(n*4+dt)*64+K32 : lane g*16+cn holds Vt[n][dt*16+cn][K32*32+g*8 ..+7]
__global__ __launch_bounds__(256) void repack_kv(
    const unsigned short* __restrict__ Kh, const unsigned short* __restrict__ Vt,
    unsigned short* __restrict__ Kf, unsigned short* __restrict__ Vf)
{
    int Wv = blockIdx.x * 4 + (threadIdx.x >> 6);   // 0..16383
    int lane = threadIdx.x & 63, cn = lane & 15, g = lane >> 4;
    if (Wv < 8192) {
        int n = Wv >> 8, kt = (Wv >> 1) & 127, kc = Wv & 1;
        short8 val = *(const short8*)(Kh + ((size_t)(n * 2048 + kt * 16 + cn) * 64) + kc * 32 + g * 8);
        *(short8*)(Kf + (size_t)Wv * 512 + lane * 8) = val;
    } else {
        int cv = Wv - 8192;
        int n = cv >> 8, dt = (cv >> 6) & 3, K32 = cv & 63;
        short8 val = *(const short8*)(Vt + ((size_t)(n * 64 + dt * 16 + cn) * 2048) + K32 * 32 + g * 8);
        *(short8*)(Vf + (size_t)cv * 512 + lane * 8) = val;
    }
}

// ---------- Kernel 2: flash attention (in-block key-split, 4x occupancy) ----
// Each block: 32 q-rows, 4 waves partition the 2048 keys (8 t-iters/wave).
// Fixed-offset exp2 (FIXMAX2) => per-wave partial (O_num, l) are exactly
// summable; 4-barrier serial LDS chain combines them at the end.
// Grid (64,32) = 2048 blocks -> 8 blocks/CU (vs 2 before): latency hiding
// by TLP instead of exposed dependence chains. Main loop stays barrier-free.
__global__ __launch_bounds__(256, 4) void flash_attn_k(
    const unsigned short* __restrict__ Qh, const unsigned short* __restrict__ Kf,
    const unsigned short* __restrict__ Vf, unsigned short* __restrict__ Oh)
{
    const int n = blockIdx.y, q0 = blockIdx.x * 32;
    __shared__ unsigned short Ps[128 * 72];      // per-wave 32-row regions; reused as fp32 combine buf

    const int tid = threadIdx.x, lane = tid & 63, w = tid >> 6;
    const int cn = lane & 15, g = lane >> 4;

    short8 ones;
    #pragma unroll
    for (int j = 0; j < 8; ++j) ones[j] = (short)0x3F80;   // bf16 1.0

    short8 qf[2][2];
    #pragma unroll
    for (int i = 0; i < 2; ++i)
        #pragma unroll
        for (int kc = 0; kc < 2; ++kc)
            qf[i][kc] = *(const short8*)(Qh + ((size_t)n * L_SEQ + q0 + i * 16 + cn) * HD + kc * 32 + g * 8);

    floatx4 acc_o[2][4], acc_l[2];
    #pragma unroll
    for (int i = 0; i < 2; ++i) {
        acc_l[i] = (floatx4){0.f, 0.f, 0.f, 0.f};
        #pragma unroll
        for (int d = 0; d < 4; ++d) acc_o[i][d] = (floatx4){0.f, 0.f, 0.f, 0.f};
    }

    const unsigned short* Kbase = Kf + (size_t)n * 131072;   // n*256 chunks
    const unsigned short* Vbase = Vf + (size_t)n * 131072;

    // this wave's key range: t in [w*8, w*8+8)
    for (int t = w * 8; t < w * 8 + 8; ++t) {
        // coalesced fragment loads (1KB per instruction)
        short8 kf[2][4], vf[4][2];
        #pragma unroll
        for (int kc = 0; kc < 2; ++kc)
            #pragma unroll
            for (int j = 0; j < 4; ++j)
                kf[kc][j] = *(const short8*)(Kbase + (size_t)(((t * 4 + j) * 2 + kc) * 512) + lane * 8);
        #pragma unroll
        for (int d = 0; d < 4; ++d)
            #pragma unroll
            for (int kc = 0; kc < 2; ++kc)
                vf[d][kc] = *(const short8*)(Vbase + (size_t)((d * 64 + t * 2 + kc) * 512) + lane * 8);

        // S^T = K Q^T : rows=keys, cols=q (this block's 32 q)
        floatx4 s[2][4];
        #pragma unroll
        for (int i = 0; i < 2; ++i)
            #pragma unroll
            for (int j = 0; j < 4; ++j) s[i][j] = (floatx4){0.f, 0.f, 0.f, 0.f};
        __builtin_amdgcn_s_setprio(1);
        #pragma unroll
        for (int kc = 0; kc < 2; ++kc)
            #pragma unroll
            for (int i = 0; i < 2; ++i)
                #pragma unroll
                for (int j = 0; j < 4; ++j)
                    s[i][j] = __builtin_amdgcn_mfma_f32_16x16x32_bf16(kf[kc][j], qf[i][kc], s[i][j], 0, 0, 0);
        __builtin_amdgcn_s_setprio(0);

        // p = exp2(s - FIXMAX2); C-layout -> A-layout via per-wave Ps region
        #pragma unroll
        for (int i = 0; i < 2; ++i)
            #pragma unroll
            for (int j = 0; j < 4; ++j) {
                float p0 = fexp2(s[i][j][0] - FIXMAX2);
                float p1 = fexp2(s[i][j][1] - FIXMAX2);
                float p2 = fexp2(s[i][j][2] - FIXMAX2);
                float p3 = fexp2(s[i][j][3] - FIXMAX2);
                *(uint2*)&Ps[(w * 32 + i * 16 + cn) * 72 + j * 16 + g * 4] =
                    make_uint2(pkbf2(p0, p1), pkbf2(p2, p3));
            }

        // O += P V ; l += P * ones
        #pragma unroll
        for (int kc = 0; kc < 2; ++kc) {
            short8 pa[2];
            #pragma unroll
            for (int i = 0; i < 2; ++i)
                pa[i] = *(const short8*)&Ps[(w * 32 + i * 16 + cn) * 72 + kc * 32 + g * 8];
            __builtin_amdgcn_s_setprio(1);
            #pragma unroll
            for (int i = 0; i < 2; ++i) {
                #pragma unroll
                for (int d = 0; d < 4; ++d)
                    acc_o[i][d] = __builtin_amdgcn_mfma_f32_16x16x32_bf16(pa[i], vf[d][kc], acc_o[i][d], 0, 0, 0);
                acc_l[i] = __builtin_amdgcn_mfma_f32_16x16x32_bf16(pa[i], ones, acc_l[i], 0, 0, 0);
            }
            __builtin_amdgcn_s_setprio(0);
        }
    }

    // ---- cross-wave combine: serial chain w3 -> w2 -> w1 -> w0 (exact sums) ----
    // fp32 staging in the dead Ps buffer; stride 41 dwords => conflict-free.
    float* U = (float*)Ps;
    const int ub = lane * 41;

#define STORE40() do {                                                     \
    _Pragma("unroll")                                                      \
    for (int i = 0; i < 2; ++i) {                                          \
        _Pragma("unroll")                                                  \
        for (int d = 0; d < 4; ++d)                                        \
            _Pragma("unroll")                                              \
            for (int r = 0; r < 4; ++r)                                    \
                U[ub + i * 20 + d * 4 + r] = acc_o[i][d][r];               \
        _Pragma("unroll")                                                  \
        for (int r = 0; r < 4; ++r)                                        \
            U[ub + i * 20 + 16 + r] = acc_l[i][r];                         \
    }                                                                      \
} while (0)

#define ADD40() do {                                                       \
    _Pragma("unroll")                                                      \
    for (int i = 0; i < 2; ++i) {                                          \
        _Pragma("unroll")                                                  \
        for (int d = 0; d < 4; ++d)                                        \
            _Pragma("unroll")                                              \
            for (int r = 0; r < 4; ++r)                                    \
                acc_o[i][d][r] += U[ub + i * 20 + d * 4 + r];              \
        _Pragma("unroll")                                                  \
        for (int r = 0; r < 4; ++r)                                        \
            acc_l[i][r] += U[ub + i * 20 + 16 + r];                        \
    }                                                                      \
} while (0)

    __syncthreads();                 // all waves done with Ps
    if (w == 3) STORE40();
    __syncthreads();
    if (w == 2) { ADD40(); STORE40(); }
    __syncthreads();
    if (w == 1) { ADD40(); STORE40(); }
    __syncthreads();
    if (w == 0) {
        ADD40();
        // epilogue: O[q][d] / l -> Oh[l][b][e]
        const int bb = n >> 4, h = n & 15;
        #pragma unroll
        for (int i = 0; i < 2; ++i)
            #pragma unroll
            for (int r = 0; r < 4; ++r) {
                float inv = 1.0f / acc_l[i][r];
                int l = q0 + i * 16 + g * 4 + r;
                #pragma unroll
                for (int d = 0; d < 4; ++d) {
                    int e = h * 64 + d * 16 + cn;
                    Oh[((size_t)l * 2 + bb) * EMB + e] = f2bf(acc_o[i][d][r] * inv);
                }
            }
    }
#undef STORE40
#undef ADD40
}

// ---------- Kernel 3: output projection (all-bf16) ----------
__global__ __launch_bounds__(256, 3) void out_gemm(
    const unsigned short* __restrict__ Oh, const unsigned short* __restrict__ Wob,
    const float* __restrict__ bo, float* __restrict__ out)
{
    __shared__ unsigned short As[128 * 64];
    __shared__ unsigned short Bs[128 * 64];

    const int tid = threadIdx.x, lane = tid & 63, w = tid >> 6;
    const int wm = (w & 1) * 64, wn = (w >> 1) * 64;
    const int m0 = blockIdx.x * 128, n0 = blockIdx.y * 128;
    const int cn = lane & 15, g = lane >> 4;

    floatx4 acc[4][4];
    #pragma unroll
    for (int i = 0; i < 4; ++i)
        #pragma unroll
        for (int j = 0; j < 4; ++j) acc[i][j] = (floatx4){0.f, 0.f, 0.f, 0.f};

    for (int k0 = 0; k0 < EMB; k0 += 64) {
        __syncthreads();
        #pragma unroll
        for (int p = 0; p < 4; ++p) {
            int u0 = (p * 4 + w) * 64, u = u0 + lane, row = u >> 3, sl = u & 7;
            gld_lds16(Oh  + (size_t)(m0 + row) * EMB + k0 + ((sl ^ (row & 7)) * 8), &As[u0 * 8]);
            gld_lds16(Wob + (size_t)(n0 + row) * EMB + k0 + ((sl ^ (row & 7)) * 8), &Bs[u0 * 8]);
        }
        __syncthreads();
        #pragma unroll
        for (int kc = 0; kc < 2; ++kc) {
            short8 a4[4], b4[4];
            #pragma unroll
            for (int i = 0; i < 4; ++i)
                a4[i] = *(const short8*)&As[(wm + i * 16 + cn) * 64 + (((kc * 4 + g) ^ (cn & 7)) * 8)];
            #pragma unroll
            for (int j = 0; j < 4; ++j)
                b4[j] = *(const short8*)&Bs[(wn + j * 16 + cn) * 64 + (((kc * 4 + g) ^ (cn & 7)) * 8)];
            #pragma unroll
            for (int i = 0; i < 4; ++i)
                #pragma unroll
                for (int j = 0; j < 4; ++j)
                    acc[i][j] = __builtin_amdgcn_mfma_f32_16x16x32_bf16(a4[i], b4[j], acc[i][j], 0, 0, 0);
        }
    }

    #pragma unroll
    for (int j = 0; j < 4; ++j) {
        int col = n0 + wn + j * 16 + cn;
        float bv = bo[col];
        #pragma unroll
        for (int i = 0; i < 4; ++i)
            #pragma unroll
            for (int r = 0; r < 4; ++r)
                out[(size_t)(m0 + wm + i * 16 + g * 4 + r) * EMB + col] = acc[i][j][r] + bv;
    }
}

extern "C" void kernel_launch(void* const* d_in, const int* in_sizes, int n_in,
                              void* d_out, int out_size, void* d_ws, size_t ws_size,
                              hipStream_t stream) {
    const float* q   = (const float*)d_in[0];
    const float* k   = (const float*)d_in[1];
    const float* v   = (const float*)d_in[2];
    const float* ipw = (const float*)d_in[3];
    const float* ipb = (const float*)d_in[4];
    const float* opw = (const float*)d_in[5];
    const float* opb = (const float*)d_in[6];
    float* out = (float*)d_out;

    const size_t HE = (size_t)32 * L_SEQ * HD;           // 4,194,304 shorts
    unsigned short* Qh   = (unsigned short*)d_ws;        // 8 MB
    unsigned short* Kh   = Qh + HE;                      // 8 MB
    unsigned short* Vt   = Kh + HE;                      // 8 MB
    unsigned short* Wipb = Vt + HE;                      // 6 MB
    unsigned short* Wopb = Wipb + (size_t)3 * EMB * EMB; // 2 MB
    unsigned short* Abq  = Wopb + (size_t)EMB * EMB;     // 8 MB
    unsigned short* Abk  = Abq + HE;                     // 8 MB
    unsigned short* Abv  = Abk + HE;                     // 8 MB  (total 56 MB)
    unsigned short* Oh   = Abq;                          // dead after qkv_gemm
    unsigned short* Kf   = Abk;                          // dead after qkv_gemm
    unsigned short* Vf   = Abv;                          // dead after qkv_gemm

    convert_all<<<dim3(16384), 256, 0, stream>>>(q, k, v, ipw, opw, Abq, Abk, Abv, Wipb, Wopb);
    qkv_gemm<<<dim3(32, 24), 256, 0, stream>>>(Abq, Abk, Abv, Wipb, ipb, Qh, Kh, Vt);
    repack_kv<<<dim3(4096), 256, 0, stream>>>(Kh, Vt, Kf, Vf);
    flash_attn_k<<<dim3(64, 32), 256, 0, stream>>>(Qh, Kf, Vf, Oh);
    out_gemm<<<dim3(32, 8), 256, 0, stream>>>(Oh, Wopb, opb, out);
}

// Round 2
// 221.184 us; speedup vs baseline: 1.3929x; 1.3929x over previous
//
#include <hip/hip_runtime.h>
#include <hip/hip_bf16.h>

typedef __attribute__((ext_vector_type(8))) short short8;
typedef __attribute__((ext_vector_type(4))) float floatx4;

#define L_SEQ 2048
#define EMB   1024
#define HD    64
#define QSCALE 0.18033688011112042f   /* 0.125 * log2(e) */
#define FIXMAX2 11.541560327111707f   /* 8 * log2(e) */

__device__ __forceinline__ unsigned short f2bf(float f) {
    unsigned int u = __float_as_uint(f);
    u += 0x7fffu + ((u >> 16) & 1u);   // RNE
    return (unsigned short)(u >> 16);
}
__device__ __forceinline__ unsigned pkbf(float a, float b) {
    return (unsigned)f2bf(a) | ((unsigned)f2bf(b) << 16);
}
__device__ __forceinline__ unsigned pkbf2(float a, float b) {
    __hip_bfloat162 h = __float22bfloat162_rn(make_float2(a, b));
    unsigned u; __builtin_memcpy(&u, &h, 4); return u;
}
__device__ __forceinline__ void gld_lds16(const void* g, void* l) {
    __builtin_amdgcn_global_load_lds(
        (const __attribute__((address_space(1))) unsigned*)g,
        (__attribute__((address_space(3))) unsigned*)l, 16, 0, 0);
}
__device__ __forceinline__ float fexp2(float x) {
    return __builtin_amdgcn_exp2f(x);   // v_exp_f32 (2^x)
}

// ---------- Kernel 0: convert weights + activations fp32 -> bf16 ----------
__global__ __launch_bounds__(256) void convert_all(
    const float* __restrict__ q, const float* __restrict__ k,
    const float* __restrict__ v, const float* __restrict__ ipw,
    const float* __restrict__ opw,
    unsigned short* __restrict__ Abq, unsigned short* __restrict__ Abk,
    unsigned short* __restrict__ Abv, unsigned short* __restrict__ Wipb,
    unsigned short* __restrict__ Wopb)
{
    const int NA = 1048576, NIP = 786432;        // float4 units
    int idx = blockIdx.x * 256 + threadIdx.x;    // 0 .. 4194303
    const float* src; unsigned short* dst; int o;
    if (idx < NA)            { src = q;   dst = Abq;  o = idx; }
    else if (idx < 2 * NA)   { src = k;   dst = Abk;  o = idx - NA; }
    else if (idx < 3 * NA)   { src = v;   dst = Abv;  o = idx - 2 * NA; }
    else if (idx < 3 * NA + NIP) { src = ipw; dst = Wipb; o = idx - 3 * NA; }
    else                     { src = opw; dst = Wopb; o = idx - 3 * NA - NIP; }
    float4 f = ((const float4*)src)[o];
    ((uint2*)dst)[o] = make_uint2(pkbf(f.x, f.y), pkbf(f.z, f.w));
}

// ---------- Kernel 1: QKV projection, all-bf16 (N=3072) ----------
__global__ __launch_bounds__(256, 3) void qkv_gemm(
    const unsigned short* __restrict__ Abq, const unsigned short* __restrict__ Abk,
    const unsigned short* __restrict__ Abv, const unsigned short* __restrict__ Wb,
    const float* __restrict__ Bip,
    unsigned short* __restrict__ Qh, unsigned short* __restrict__ Kh,
    unsigned short* __restrict__ Vt)
{
    __shared__ unsigned short lds[17408];
    unsigned short* As = lds;
    unsigned short* Bs = lds + 8192;

    const int tid = threadIdx.x, lane = tid & 63, w = tid >> 6;
    const int wm = (w & 1) * 64, wn = (w >> 1) * 64;
    const int m0 = blockIdx.x * 128, n0 = blockIdx.y * 128;
    const int cn = lane & 15, g = lane >> 4;
    const int z = n0 >> 10;
    const unsigned short* Ag = (z == 0) ? Abq : (z == 1) ? Abk : Abv;

    floatx4 acc[4][4];
    #pragma unroll
    for (int i = 0; i < 4; ++i)
        #pragma unroll
        for (int j = 0; j < 4; ++j) acc[i][j] = (floatx4){0.f, 0.f, 0.f, 0.f};

    for (int k0 = 0; k0 < EMB; k0 += 64) {
        __syncthreads();
        #pragma unroll
        for (int p = 0; p < 4; ++p) {
            int u0 = (p * 4 + w) * 64, u = u0 + lane, row = u >> 3, sl = u & 7;
            gld_lds16(Ag + (size_t)(m0 + row) * EMB + k0 + ((sl ^ (row & 7)) * 8), &As[u0 * 8]);
            gld_lds16(Wb + (size_t)(n0 + row) * EMB + k0 + ((sl ^ (row & 7)) * 8), &Bs[u0 * 8]);
        }
        __syncthreads();
        #pragma unroll
        for (int kc = 0; kc < 2; ++kc) {
            short8 a4[4], b4[4];
            #pragma unroll
            for (int i = 0; i < 4; ++i)
                a4[i] = *(const short8*)&As[(wm + i * 16 + cn) * 64 + (((kc * 4 + g) ^ (cn & 7)) * 8)];
            #pragma unroll
            for (int j = 0; j < 4; ++j)
                b4[j] = *(const short8*)&Bs[(wn + j * 16 + cn) * 64 + (((kc * 4 + g) ^ (cn & 7)) * 8)];
            #pragma unroll
            for (int i = 0; i < 4; ++i)
                #pragma unroll
                for (int j = 0; j < 4; ++j)
                    acc[i][j] = __builtin_amdgcn_mfma_f32_16x16x32_bf16(a4[i], b4[j], acc[i][j], 0, 0, 0);
        }
    }

    if (z < 2) {
        #pragma unroll
        for (int j = 0; j < 4; ++j) {
            int col = n0 + wn + j * 16 + cn;
            float bv = Bip[col];
            int o = col & 1023, h = o >> 6, d = o & 63;
            #pragma unroll
            for (int i = 0; i < 4; ++i)
                #pragma unroll
                for (int r = 0; r < 4; ++r) {
                    int rr = m0 + wm + i * 16 + g * 4 + r;   // l*2 + b
                    float vv = acc[i][j][r] + bv;
                    int l = rr >> 1, bb = rr & 1, nn = bb * 16 + h;
                    if (z == 0) Qh[((size_t)nn * L_SEQ + l) * HD + d] = f2bf(vv * QSCALE);
                    else        Kh[((size_t)nn * L_SEQ + l) * HD + d] = f2bf(vv);
                }
        }
    } else {
        // z==2: LDS-transposed epilogue -> Vt[n][d][l] coalesced 16B stores
        __syncthreads();
        #pragma unroll
        for (int j = 0; j < 4; ++j) {
            int col_l = wn + j * 16 + cn;
            float bv = Bip[n0 + col_l];
            #pragma unroll
            for (int i = 0; i < 4; ++i) {
                int rrb = wm + i * 16 + g * 4;
                int l0 = rrb >> 1;
                float v0 = acc[i][j][0] + bv, v1 = acc[i][j][1] + bv;
                float v2 = acc[i][j][2] + bv, v3 = acc[i][j][3] + bv;
                *(unsigned*)&lds[col_l * 136 +      l0] = pkbf(v0, v2);
                *(unsigned*)&lds[col_l * 136 + 64 + l0] = pkbf(v1, v3);
            }
        }
        __syncthreads();
        int cl = tid >> 1, bb = tid & 1;
        int o = (n0 - 2048) + cl, h = o >> 6, d = o & 63;
        int nn = bb * 16 + h;
        unsigned short* dst = Vt + ((size_t)nn * HD + d) * L_SEQ + (m0 >> 1);
        const unsigned short* srcp = &lds[cl * 136 + bb * 64];
        #pragma unroll
        for (int i = 0; i < 8; ++i)
            *(uint4*)(dst + i * 8) = *(const uint4*)(srcp + i * 8);
    }
}

// ---------- Kernel 1b: repack K,V into MFMA-fragment-contiguous chunks ------
// Kf chunk ck=(n*128+kt)*2+kc : lane g*16+cn holds Kh[n][kt*16+cn][kc*32+g*8 ..+7]
// Vf chunk cv=(n*4+dt)*64+K32 : lane g*16+cn holds Vt[n][dt*16+cn][K32*32+g*8 ..+7]
__global__ __launch_bounds__(256) void repack_kv(
    const unsigned short* __restrict__ Kh, const unsigned short* __restrict__ Vt,
    unsigned short* __restrict__ Kf, unsigned short* __restrict__ Vf)
{
    int Wv = blockIdx.x * 4 + (threadIdx.x >> 6);   // 0..16383
    int lane = threadIdx.x & 63, cn = lane & 15, g = lane >> 4;
    if (Wv < 8192) {
        int n = Wv >> 8, kt = (Wv >> 1) & 127, kc = Wv & 1;
        short8 val = *(const short8*)(Kh + ((size_t)(n * 2048 + kt * 16 + cn) * 64) + kc * 32 + g * 8);
        *(short8*)(Kf + (size_t)Wv * 512 + lane * 8) = val;
    } else {
        int cv = Wv - 8192;
        int n = cv >> 8, dt = (cv >> 6) & 3, K32 = cv & 63;
        short8 val = *(const short8*)(Vt + ((size_t)(n * 64 + dt * 16 + cn) * 2048) + K32 * 32 + g * 8);
        *(short8*)(Vf + (size_t)cv * 512 + lane * 8) = val;
    }
}

// ---------- Kernel 2: flash attention (2-way key split + XCD locality) ------
// Block = 64 q-rows, 4 waves: wave w -> q-half (w&1), key-half (w>>1).
// Each wave streams 16 t-iters (1024 keys). Fixed-offset exp2 => per-wave
// partials are exactly summable; ONE barrier + LDS add combines key-halves.
// Grid 1024 blocks -> 4 blocks/CU, 16 waves/CU (50% occ) with NO regalloc
// coercion (round-1 lesson: launch_bounds(256,4) caused ~230 MB scratch
// spill). XCD swizzle gives each XCD 4 whole heads -> ~3 MB L2 working set.
__global__ __launch_bounds__(256, 2) void flash_attn_k(
    const unsigned short* __restrict__ Qh, const unsigned short* __restrict__ Kf,
    const unsigned short* __restrict__ Vf, unsigned short* __restrict__ Oh)
{
    // XCD-aware remap of 1024 blocks (id&7 = XCD under round-robin dispatch):
    // XCD k processes heads [4k, 4k+4) only.
    const int id = blockIdx.y * 32 + blockIdx.x;
    const int xcd = id & 7, slot = id >> 3;
    const int n = xcd * 4 + (slot & 3);
    const int q0 = (slot >> 2) * 64;

    __shared__ float Uf[2 * 64 * 41];            // 20992 B combine buf; aliased as Ps
    unsigned short* Ps = (unsigned short*)Uf;    // 128x72 shorts = 18432 B used

    const int tid = threadIdx.x, lane = tid & 63, w = tid >> 6;
    const int qh = w & 1, kh = w >> 1;
    const int cn = lane & 15, g = lane >> 4;

    short8 ones;
    #pragma unroll
    for (int j = 0; j < 8; ++j) ones[j] = (short)0x3F80;   // bf16 1.0

    short8 qf[2][2];
    #pragma unroll
    for (int i = 0; i < 2; ++i)
        #pragma unroll
        for (int kc = 0; kc < 2; ++kc)
            qf[i][kc] = *(const short8*)(Qh + ((size_t)n * L_SEQ + q0 + qh * 32 + i * 16 + cn) * HD + kc * 32 + g * 8);

    floatx4 acc_o[2][4], acc_l[2];
    #pragma unroll
    for (int i = 0; i < 2; ++i) {
        acc_l[i] = (floatx4){0.f, 0.f, 0.f, 0.f};
        #pragma unroll
        for (int d = 0; d < 4; ++d) acc_o[i][d] = (floatx4){0.f, 0.f, 0.f, 0.f};
    }

    const unsigned short* Kbase = Kf + (size_t)n * 131072;   // n*256 chunks
    const unsigned short* Vbase = Vf + (size_t)n * 131072;

    // this wave's key range: t in [kh*16, kh*16+16)
    for (int t = kh * 16; t < kh * 16 + 16; ++t) {
        // coalesced fragment loads (1KB per instruction, L2-resident)
        short8 kf[2][4], vf[4][2];
        #pragma unroll
        for (int kc = 0; kc < 2; ++kc)
            #pragma unroll
            for (int j = 0; j < 4; ++j)
                kf[kc][j] = *(const short8*)(Kbase + (size_t)(((t * 4 + j) * 2 + kc) * 512) + lane * 8);
        #pragma unroll
        for (int d = 0; d < 4; ++d)
            #pragma unroll
            for (int kc = 0; kc < 2; ++kc)
                vf[d][kc] = *(const short8*)(Vbase + (size_t)((d * 64 + t * 2 + kc) * 512) + lane * 8);

        // S^T = K Q^T : rows=keys, cols=q (this wave's 32 q)
        floatx4 s[2][4];
        #pragma unroll
        for (int i = 0; i < 2; ++i)
            #pragma unroll
            for (int j = 0; j < 4; ++j) s[i][j] = (floatx4){0.f, 0.f, 0.f, 0.f};
        __builtin_amdgcn_s_setprio(1);
        #pragma unroll
        for (int kc = 0; kc < 2; ++kc)
            #pragma unroll
            for (int i = 0; i < 2; ++i)
                #pragma unroll
                for (int j = 0; j < 4; ++j)
                    s[i][j] = __builtin_amdgcn_mfma_f32_16x16x32_bf16(kf[kc][j], qf[i][kc], s[i][j], 0, 0, 0);
        __builtin_amdgcn_s_setprio(0);

        // p = exp2(s - FIXMAX2); C-layout -> A-layout via per-wave Ps region
        #pragma unroll
        for (int i = 0; i < 2; ++i)
            #pragma unroll
            for (int j = 0; j < 4; ++j) {
                float p0 = fexp2(s[i][j][0] - FIXMAX2);
                float p1 = fexp2(s[i][j][1] - FIXMAX2);
                float p2 = fexp2(s[i][j][2] - FIXMAX2);
                float p3 = fexp2(s[i][j][3] - FIXMAX2);
                *(uint2*)&Ps[(w * 32 + i * 16 + cn) * 72 + j * 16 + g * 4] =
                    make_uint2(pkbf2(p0, p1), pkbf2(p2, p3));
            }

        // O += P V ; l += P * ones
        #pragma unroll
        for (int kc = 0; kc < 2; ++kc) {
            short8 pa[2];
            #pragma unroll
            for (int i = 0; i < 2; ++i)
                pa[i] = *(const short8*)&Ps[(w * 32 + i * 16 + cn) * 72 + kc * 32 + g * 8];
            __builtin_amdgcn_s_setprio(1);
            #pragma unroll
            for (int i = 0; i < 2; ++i) {
                #pragma unroll
                for (int d = 0; d < 4; ++d)
                    acc_o[i][d] = __builtin_amdgcn_mfma_f32_16x16x32_bf16(pa[i], vf[d][kc], acc_o[i][d], 0, 0, 0);
                acc_l[i] = __builtin_amdgcn_mfma_f32_16x16x32_bf16(pa[i], ones, acc_l[i], 0, 0, 0);
            }
            __builtin_amdgcn_s_setprio(0);
        }
    }

    // ---- cross-wave combine: key-half partners (w, w+2) share q-rows ----
    // fp32 staging, stride 41 dwords => conflict-free.
    const int ub = qh * (64 * 41) + lane * 41;

    __syncthreads();                 // all waves done with Ps
    if (kh) {                        // waves 2,3 store partials
        #pragma unroll
        for (int i = 0; i < 2; ++i) {
            #pragma unroll
            for (int d = 0; d < 4; ++d)
                #pragma unroll
                for (int r = 0; r < 4; ++r)
                    Uf[ub + i * 20 + d * 4 + r] = acc_o[i][d][r];
            #pragma unroll
            for (int r = 0; r < 4; ++r)
                Uf[ub + i * 20 + 16 + r] = acc_l[i][r];
        }
    }
    __syncthreads();
    if (!kh) {                       // waves 0,1 add + epilogue
        #pragma unroll
        for (int i = 0; i < 2; ++i) {
            #pragma unroll
            for (int d = 0; d < 4; ++d)
                #pragma unroll
                for (int r = 0; r < 4; ++r)
                    acc_o[i][d][r] += Uf[ub + i * 20 + d * 4 + r];
            #pragma unroll
            for (int r = 0; r < 4; ++r)
                acc_l[i][r] += Uf[ub + i * 20 + 16 + r];
        }
        // epilogue: O[q][d] / l -> Oh[l][b][e]
        const int bb = n >> 4, h = n & 15;
        #pragma unroll
        for (int i = 0; i < 2; ++i)
            #pragma unroll
            for (int r = 0; r < 4; ++r) {
                float inv = 1.0f / acc_l[i][r];
                int l = q0 + qh * 32 + i * 16 + g * 4 + r;
                #pragma unroll
                for (int d = 0; d < 4; ++d) {
                    int e = h * 64 + d * 16 + cn;
                    Oh[((size_t)l * 2 + bb) * EMB + e] = f2bf(acc_o[i][d][r] * inv);
                }
            }
    }
}

// ---------- Kernel 3: output projection (all-bf16) ----------
__global__ __launch_bounds__(256, 3) void out_gemm(
    const unsigned short* __restrict__ Oh, const unsigned short* __restrict__ Wob,
    const float* __restrict__ bo, float* __restrict__ out)
{
    __shared__ unsigned short As[128 * 64];
    __shared__ unsigned short Bs[128 * 64];

    const int tid = threadIdx.x, lane = tid & 63, w = tid >> 6;
    const int wm = (w & 1) * 64, wn = (w >> 1) * 64;
    const int m0 = blockIdx.x * 128, n0 = blockIdx.y * 128;
    const int cn = lane & 15, g = lane >> 4;

    floatx4 acc[4][4];
    #pragma unroll
    for (int i = 0; i < 4; ++i)
        #pragma unroll
        for (int j = 0; j < 4; ++j) acc[i][j] = (floatx4){0.f, 0.f, 0.f, 0.f};

    for (int k0 = 0; k0 < EMB; k0 += 64) {
        __syncthreads();
        #pragma unroll
        for (int p = 0; p < 4; ++p) {
            int u0 = (p * 4 + w) * 64, u = u0 + lane, row = u >> 3, sl = u & 7;
            gld_lds16(Oh  + (size_t)(m0 + row) * EMB + k0 + ((sl ^ (row & 7)) * 8), &As[u0 * 8]);
            gld_lds16(Wob + (size_t)(n0 + row) * EMB + k0 + ((sl ^ (row & 7)) * 8), &Bs[u0 * 8]);
        }
        __syncthreads();
        #pragma unroll
        for (int kc = 0; kc < 2; ++kc) {
            short8 a4[4], b4[4];
            #pragma unroll
            for (int i = 0; i < 4; ++i)
                a4[i] = *(const short8*)&As[(wm + i * 16 + cn) * 64 + (((kc * 4 + g) ^ (cn & 7)) * 8)];
            #pragma unroll
            for (int j = 0; j < 4; ++j)
                b4[j] = *(const short8*)&Bs[(wn + j * 16 + cn) * 64 + (((kc * 4 + g) ^ (cn & 7)) * 8)];
            #pragma unroll
            for (int i = 0; i < 4; ++i)
                #pragma unroll
                for (int j = 0; j < 4; ++j)
                    acc[i][j] = __builtin_amdgcn_mfma_f32_16x16x32_bf16(a4[i], b4[j], acc[i][j], 0, 0, 0);
        }
    }

    #pragma unroll
    for (int j = 0; j < 4; ++j) {
        int col = n0 + wn + j * 16 + cn;
        float bv = bo[col];
        #pragma unroll
        for (int i = 0; i < 4; ++i)
            #pragma unroll
            for (int r = 0; r < 4; ++r)
                out[(size_t)(m0 + wm + i * 16 + g * 4 + r) * EMB + col] = acc[i][j][r] + bv;
    }
}

extern "C" void kernel_launch(void* const* d_in, const int* in_sizes, int n_in,
                              void* d_out, int out_size, void* d_ws, size_t ws_size,
                              hipStream_t stream) {
    const float* q   = (const float*)d_in[0];
    const float* k   = (const float*)d_in[1];
    const float* v   = (const float*)d_in[2];
    const float* ipw = (const float*)d_in[3];
    const float* ipb = (const float*)d_in[4];
    const float* opw = (const float*)d_in[5];
    const float* opb = (const float*)d_in[6];
    float* out = (float*)d_out;

    const size_t HE = (size_t)32 * L_SEQ * HD;           // 4,194,304 shorts
    unsigned short* Qh   = (unsigned short*)d_ws;        // 8 MB
    unsigned short* Kh   = Qh + HE;                      // 8 MB
    unsigned short* Vt   = Kh + HE;                      // 8 MB
    unsigned short* Wipb = Vt + HE;                      // 6 MB
    unsigned short* Wopb = Wipb + (size_t)3 * EMB * EMB; // 2 MB
    unsigned short* Abq  = Wopb + (size_t)EMB * EMB;     // 8 MB
    unsigned short* Abk  = Abq + HE;                     // 8 MB
    unsigned short* Abv  = Abk + HE;                     // 8 MB  (total 56 MB)
    unsigned short* Oh   = Abq;                          // dead after qkv_gemm
    unsigned short* Kf   = Abk;                          // dead after qkv_gemm
    unsigned short* Vf   = Abv;                          // dead after qkv_gemm

    convert_all<<<dim3(16384), 256, 0, stream>>>(q, k, v, ipw, opw, Abq, Abk, Abv, Wipb, Wopb);
    qkv_gemm<<<dim3(32, 24), 256, 0, stream>>>(Abq, Abk, Abv, Wipb, ipb, Qh, Kh, Vt);
    repack_kv<<<dim3(4096), 256, 0, stream>>>(Kh, Vt, Kf, Vf);
    flash_attn_k<<<dim3(32, 32), 256, 0, stream>>>(Qh, Kf, Vf, Oh);
    out_gemm<<<dim3(32, 8), 256, 0, stream>>>(Oh, Wopb, opb, out);
}

// Round 3
// 220.766 us; speedup vs baseline: 1.3956x; 1.0019x over previous
//
#include <hip/hip_runtime.h>
#include <hip/hip_bf16.h>

typedef __attribute__((ext_vector_type(8))) short short8;
typedef __attribute__((ext_vector_type(4))) float floatx4;

#define L_SEQ 2048
#define EMB   1024
#define HD    64
#define QSCALE 0.18033688011112042f   /* 0.125 * log2(e) */
#define FIXMAX2 11.541560327111707f   /* 8 * log2(e) */

__device__ __forceinline__ unsigned short f2bf(float f) {
    unsigned int u = __float_as_uint(f);
    u += 0x7fffu + ((u >> 16) & 1u);   // RNE
    return (unsigned short)(u >> 16);
}
__device__ __forceinline__ unsigned pkbf(float a, float b) {
    return (unsigned)f2bf(a) | ((unsigned)f2bf(b) << 16);
}
__device__ __forceinline__ unsigned pkbf2(float a, float b) {
    __hip_bfloat162 h = __float22bfloat162_rn(make_float2(a, b));
    unsigned u; __builtin_memcpy(&u, &h, 4); return u;
}
__device__ __forceinline__ void gld_lds16(const void* g, void* l) {
    __builtin_amdgcn_global_load_lds(
        (const __attribute__((address_space(1))) unsigned*)g,
        (__attribute__((address_space(3))) unsigned*)l, 16, 0, 0);
}
__device__ __forceinline__ float fexp2(float x) {
    return __builtin_amdgcn_exp2f(x);   // v_exp_f32 (2^x)
}

// ---------- Kernel 0: convert weights + activations fp32 -> bf16 ----------
__global__ __launch_bounds__(256) void convert_all(
    const float* __restrict__ q, const float* __restrict__ k,
    const float* __restrict__ v, const float* __restrict__ ipw,
    const float* __restrict__ opw,
    unsigned short* __restrict__ Abq, unsigned short* __restrict__ Abk,
    unsigned short* __restrict__ Abv, unsigned short* __restrict__ Wipb,
    unsigned short* __restrict__ Wopb)
{
    const int NA = 1048576, NIP = 786432;        // float4 units
    int idx = blockIdx.x * 256 + threadIdx.x;    // 0 .. 4194303
    const float* src; unsigned short* dst; int o;
    if (idx < NA)            { src = q;   dst = Abq;  o = idx; }
    else if (idx < 2 * NA)   { src = k;   dst = Abk;  o = idx - NA; }
    else if (idx < 3 * NA)   { src = v;   dst = Abv;  o = idx - 2 * NA; }
    else if (idx < 3 * NA + NIP) { src = ipw; dst = Wipb; o = idx - 3 * NA; }
    else                     { src = opw; dst = Wopb; o = idx - 3 * NA - NIP; }
    float4 f = ((const float4*)src)[o];
    ((uint2*)dst)[o] = make_uint2(pkbf(f.x, f.y), pkbf(f.z, f.w));
}

// ---------- Kernel 1: QKV projection, all-bf16 (N=3072) ----------
__global__ __launch_bounds__(256, 3) void qkv_gemm(
    const unsigned short* __restrict__ Abq, const unsigned short* __restrict__ Abk,
    const unsigned short* __restrict__ Abv, const unsigned short* __restrict__ Wb,
    const float* __restrict__ Bip,
    unsigned short* __restrict__ Qh, unsigned short* __restrict__ Kh,
    unsigned short* __restrict__ Vt)
{
    __shared__ unsigned short lds[17408];
    unsigned short* As = lds;
    unsigned short* Bs = lds + 8192;

    const int tid = threadIdx.x, lane = tid & 63, w = tid >> 6;
    const int wm = (w & 1) * 64, wn = (w >> 1) * 64;
    const int m0 = blockIdx.x * 128, n0 = blockIdx.y * 128;
    const int cn = lane & 15, g = lane >> 4;
    const int z = n0 >> 10;
    const unsigned short* Ag = (z == 0) ? Abq : (z == 1) ? Abk : Abv;

    floatx4 acc[4][4];
    #pragma unroll
    for (int i = 0; i < 4; ++i)
        #pragma unroll
        for (int j = 0; j < 4; ++j) acc[i][j] = (floatx4){0.f, 0.f, 0.f, 0.f};

    for (int k0 = 0; k0 < EMB; k0 += 64) {
        __syncthreads();
        #pragma unroll
        for (int p = 0; p < 4; ++p) {
            int u0 = (p * 4 + w) * 64, u = u0 + lane, row = u >> 3, sl = u & 7;
            gld_lds16(Ag + (size_t)(m0 + row) * EMB + k0 + ((sl ^ (row & 7)) * 8), &As[u0 * 8]);
            gld_lds16(Wb + (size_t)(n0 + row) * EMB + k0 + ((sl ^ (row & 7)) * 8), &Bs[u0 * 8]);
        }
        __syncthreads();
        #pragma unroll
        for (int kc = 0; kc < 2; ++kc) {
            short8 a4[4], b4[4];
            #pragma unroll
            for (int i = 0; i < 4; ++i)
                a4[i] = *(const short8*)&As[(wm + i * 16 + cn) * 64 + (((kc * 4 + g) ^ (cn & 7)) * 8)];
            #pragma unroll
            for (int j = 0; j < 4; ++j)
                b4[j] = *(const short8*)&Bs[(wn + j * 16 + cn) * 64 + (((kc * 4 + g) ^ (cn & 7)) * 8)];
            #pragma unroll
            for (int i = 0; i < 4; ++i)
                #pragma unroll
                for (int j = 0; j < 4; ++j)
                    acc[i][j] = __builtin_amdgcn_mfma_f32_16x16x32_bf16(a4[i], b4[j], acc[i][j], 0, 0, 0);
        }
    }

    if (z < 2) {
        #pragma unroll
        for (int j = 0; j < 4; ++j) {
            int col = n0 + wn + j * 16 + cn;
            float bv = Bip[col];
            int o = col & 1023, h = o >> 6, d = o & 63;
            #pragma unroll
            for (int i = 0; i < 4; ++i)
                #pragma unroll
                for (int r = 0; r < 4; ++r) {
                    int rr = m0 + wm + i * 16 + g * 4 + r;   // l*2 + b
                    float vv = acc[i][j][r] + bv;
                    int l = rr >> 1, bb = rr & 1, nn = bb * 16 + h;
                    if (z == 0) Qh[((size_t)nn * L_SEQ + l) * HD + d] = f2bf(vv * QSCALE);
                    else        Kh[((size_t)nn * L_SEQ + l) * HD + d] = f2bf(vv);
                }
        }
    } else {
        // z==2: LDS-transposed epilogue -> Vt[n][d][l] coalesced 16B stores
        __syncthreads();
        #pragma unroll
        for (int j = 0; j < 4; ++j) {
            int col_l = wn + j * 16 + cn;
            float bv = Bip[n0 + col_l];
            #pragma unroll
            for (int i = 0; i < 4; ++i) {
                int rrb = wm + i * 16 + g * 4;
                int l0 = rrb >> 1;
                float v0 = acc[i][j][0] + bv, v1 = acc[i][j][1] + bv;
                float v2 = acc[i][j][2] + bv, v3 = acc[i][j][3] + bv;
                *(unsigned*)&lds[col_l * 136 +      l0] = pkbf(v0, v2);
                *(unsigned*)&lds[col_l * 136 + 64 + l0] = pkbf(v1, v3);
            }
        }
        __syncthreads();
        int cl = tid >> 1, bb = tid & 1;
        int o = (n0 - 2048) + cl, h = o >> 6, d = o & 63;
        int nn = bb * 16 + h;
        unsigned short* dst = Vt + ((size_t)nn * HD + d) * L_SEQ + (m0 >> 1);
        const unsigned short* srcp = &lds[cl * 136 + bb * 64];
        #pragma unroll
        for (int i = 0; i < 8; ++i)
            *(uint4*)(dst + i * 8) = *(const uint4*)(srcp + i * 8);
    }
}

// ---------- Kernel 1b: repack K,V into MFMA-fragment-contiguous chunks ------
// Kf chunk ck=(n*128+kt)*2+kc : lane g*16+cn holds Kh[n][kt*16+cn][kc*32+g*8 ..+7]
// Vf chunk cv=(n*4+dt)*64+K32 : lane g*16+cn holds Vt[n][dt*16+cn][K32*32+g*8 ..+7]
__global__ __launch_bounds__(256) void repack_kv(
    const unsigned short* __restrict__ Kh, const unsigned short* __restrict__ Vt,
    unsigned short* __restrict__ Kf, unsigned short* __restrict__ Vf)
{
    int Wv = blockIdx.x * 4 + (threadIdx.x >> 6);   // 0..16383
    int lane = threadIdx.x & 63, cn = lane & 15, g = lane >> 4;
    if (Wv < 8192) {
        int n = Wv >> 8, kt = (Wv >> 1) & 127, kc = Wv & 1;
        short8 val = *(const short8*)(Kh + ((size_t)(n * 2048 + kt * 16 + cn) * 64) + kc * 32 + g * 8);
        *(short8*)(Kf + (size_t)Wv * 512 + lane * 8) = val;
    } else {
        int cv = Wv - 8192;
        int n = cv >> 8, dt = (cv >> 6) & 3, K32 = cv & 63;
        short8 val = *(const short8*)(Vt + ((size_t)(n * 64 + dt * 16 + cn) * 2048) + K32 * 32 + g * 8);
        *(short8*)(Vf + (size_t)cv * 512 + lane * 8) = val;
    }
}

// ---------- Kernel 2: flash attention (64q/wave, 4-way key split) -----------
// Block = 64 q-rows shared by 4 waves; wave w owns keys [w*512,(w+1)*512).
// Doubling q-per-wave halves L2 fragment traffic per FLOP (1.07GB -> 537MB);
// that traffic ran at ~60% of the per-XCD L2 ceiling in round 2.
// S-phase is j-streamed (load 2KB -> 8 MFMA -> exp -> pack) to cap live regs.
// Fixed-offset exp2 => per-wave partials exactly summable; 3-step serial LDS
// combine. NO launch-bounds regalloc coercion (round-1 spill lesson).
__global__ __launch_bounds__(256, 2) void flash_attn_k(
    const unsigned short* __restrict__ Qh, const unsigned short* __restrict__ Kf,
    const unsigned short* __restrict__ Vf, unsigned short* __restrict__ Oh)
{
    // XCD-aware remap of 1024 blocks: XCD k -> heads [4k,4k+4) (~3MB L2 set).
    const int id = blockIdx.y * 32 + blockIdx.x;
    const int xcd = id & 7, slot = id >> 3;
    const int n = xcd * 4 + (slot & 3);
    const int q0 = (slot >> 2) * 64;

    __shared__ unsigned short Ps[4 * 64 * 72];   // 36864 B; aliased as combine buf
    float* Uf = (float*)Ps;

    const int tid = threadIdx.x, lane = tid & 63, w = tid >> 6;
    const int cn = lane & 15, g = lane >> 4;

    short8 ones;
    #pragma unroll
    for (int j = 0; j < 8; ++j) ones[j] = (short)0x3F80;   // bf16 1.0

    short8 qf[4][2];
    #pragma unroll
    for (int i = 0; i < 4; ++i)
        #pragma unroll
        for (int kc = 0; kc < 2; ++kc)
            qf[i][kc] = *(const short8*)(Qh + ((size_t)n * L_SEQ + q0 + i * 16 + cn) * HD + kc * 32 + g * 8);

    floatx4 acc_o[4][4], acc_l[4];
    #pragma unroll
    for (int i = 0; i < 4; ++i) {
        acc_l[i] = (floatx4){0.f, 0.f, 0.f, 0.f};
        #pragma unroll
        for (int d = 0; d < 4; ++d) acc_o[i][d] = (floatx4){0.f, 0.f, 0.f, 0.f};
    }

    const unsigned short* Kbase = Kf + (size_t)n * 131072;   // n*256 chunks
    const unsigned short* Vbase = Vf + (size_t)n * 131072;

    // this wave's key range: t in [w*8, w*8+8)
    for (int t = w * 8; t < w * 8 + 8; ++t) {
        // ---- S^T = K Q^T, streamed per 16-key subtile j ----
        #pragma unroll
        for (int j = 0; j < 4; ++j) {
            short8 kf0 = *(const short8*)(Kbase + (size_t)((((t * 4 + j) * 2 + 0) * 512)) + lane * 8);
            short8 kf1 = *(const short8*)(Kbase + (size_t)((((t * 4 + j) * 2 + 1) * 512)) + lane * 8);
            floatx4 sj[4];
            __builtin_amdgcn_s_setprio(1);
            #pragma unroll
            for (int i = 0; i < 4; ++i) {
                sj[i] = __builtin_amdgcn_mfma_f32_16x16x32_bf16(kf0, qf[i][0], (floatx4){0.f, 0.f, 0.f, 0.f}, 0, 0, 0);
                sj[i] = __builtin_amdgcn_mfma_f32_16x16x32_bf16(kf1, qf[i][1], sj[i], 0, 0, 0);
            }
            __builtin_amdgcn_s_setprio(0);
            #pragma unroll
            for (int i = 0; i < 4; ++i) {
                float p0 = fexp2(sj[i][0] - FIXMAX2);
                float p1 = fexp2(sj[i][1] - FIXMAX2);
                float p2 = fexp2(sj[i][2] - FIXMAX2);
                float p3 = fexp2(sj[i][3] - FIXMAX2);
                *(uint2*)&Ps[(w * 64 + i * 16 + cn) * 72 + j * 16 + g * 4] =
                    make_uint2(pkbf2(p0, p1), pkbf2(p2, p3));
            }
        }

        // ---- O += P V ; l += P * ones ----
        #pragma unroll
        for (int kc = 0; kc < 2; ++kc) {
            short8 vf[4];
            #pragma unroll
            for (int d = 0; d < 4; ++d)
                vf[d] = *(const short8*)(Vbase + (size_t)((d * 64 + t * 2 + kc) * 512) + lane * 8);
            short8 pa[4];
            #pragma unroll
            for (int i = 0; i < 4; ++i)
                pa[i] = *(const short8*)&Ps[(w * 64 + i * 16 + cn) * 72 + kc * 32 + g * 8];
            __builtin_amdgcn_s_setprio(1);
            #pragma unroll
            for (int i = 0; i < 4; ++i) {
                #pragma unroll
                for (int d = 0; d < 4; ++d)
                    acc_o[i][d] = __builtin_amdgcn_mfma_f32_16x16x32_bf16(pa[i], vf[d], acc_o[i][d], 0, 0, 0);
                acc_l[i] = __builtin_amdgcn_mfma_f32_16x16x32_bf16(pa[i], ones, acc_l[i], 0, 0, 0);
            }
            __builtin_amdgcn_s_setprio(0);
        }
    }

    // ---- cross-wave combine: serial chain w3 -> w2 -> w1 -> w0 (exact) ----
    // fp32 staging in dead Ps; stride 81 dwords (odd) => <=2 lanes/bank (free).
    const int ub = lane * 81;

    __syncthreads();                 // all waves done with Ps
    if (w == 3) {
        #pragma unroll
        for (int i = 0; i < 4; ++i) {
            #pragma unroll
            for (int d = 0; d < 4; ++d)
                #pragma unroll
                for (int r = 0; r < 4; ++r)
                    Uf[ub + i * 20 + d * 4 + r] = acc_o[i][d][r];
            #pragma unroll
            for (int r = 0; r < 4; ++r)
                Uf[ub + i * 20 + 16 + r] = acc_l[i][r];
        }
    }
    __syncthreads();
    if (w == 2 || w == 1) {
        // w==2 first (w==1 waits one more barrier below via divergence-free order)
    }
    if (w == 2) {
        #pragma unroll
        for (int i = 0; i < 4; ++i) {
            #pragma unroll
            for (int d = 0; d < 4; ++d)
                #pragma unroll
                for (int r = 0; r < 4; ++r)
                    acc_o[i][d][r] += Uf[ub + i * 20 + d * 4 + r];
            #pragma unroll
            for (int r = 0; r < 4; ++r)
                acc_l[i][r] += Uf[ub + i * 20 + 16 + r];
        }
        #pragma unroll
        for (int i = 0; i < 4; ++i) {
            #pragma unroll
            for (int d = 0; d < 4; ++d)
                #pragma unroll
                for (int r = 0; r < 4; ++r)
                    Uf[ub + i * 20 + d * 4 + r] = acc_o[i][d][r];
            #pragma unroll
            for (int r = 0; r < 4; ++r)
                Uf[ub + i * 20 + 16 + r] = acc_l[i][r];
        }
    }
    __syncthreads();
    if (w == 1) {
        #pragma unroll
        for (int i = 0; i < 4; ++i) {
            #pragma unroll
            for (int d = 0; d < 4; ++d)
                #pragma unroll
                for (int r = 0; r < 4; ++r)
                    acc_o[i][d][r] += Uf[ub + i * 20 + d * 4 + r];
            #pragma unroll
            for (int r = 0; r < 4; ++r)
                acc_l[i][r] += Uf[ub + i * 20 + 16 + r];
        }
        #pragma unroll
        for (int i = 0; i < 4; ++i) {
            #pragma unroll
            for (int d = 0; d < 4; ++d)
                #pragma unroll
                for (int r = 0; r < 4; ++r)
                    Uf[ub + i * 20 + d * 4 + r] = acc_o[i][d][r];
            #pragma unroll
            for (int r = 0; r < 4; ++r)
                Uf[ub + i * 20 + 16 + r] = acc_l[i][r];
        }
    }
    __syncthreads();
    if (w == 0) {
        #pragma unroll
        for (int i = 0; i < 4; ++i) {
            #pragma unroll
            for (int d = 0; d < 4; ++d)
                #pragma unroll
                for (int r = 0; r < 4; ++r)
                    acc_o[i][d][r] += Uf[ub + i * 20 + d * 4 + r];
            #pragma unroll
            for (int r = 0; r < 4; ++r)
                acc_l[i][r] += Uf[ub + i * 20 + 16 + r];
        }
        // epilogue: O[q][d] / l -> Oh[l][b][e]
        const int bb = n >> 4, h = n & 15;
        #pragma unroll
        for (int i = 0; i < 4; ++i)
            #pragma unroll
            for (int r = 0; r < 4; ++r) {
                float inv = 1.0f / acc_l[i][r];
                int l = q0 + i * 16 + g * 4 + r;
                #pragma unroll
                for (int d = 0; d < 4; ++d) {
                    int e = h * 64 + d * 16 + cn;
                    Oh[((size_t)l * 2 + bb) * EMB + e] = f2bf(acc_o[i][d][r] * inv);
                }
            }
    }
}

// ---------- Kernel 3: output projection (all-bf16) ----------
__global__ __launch_bounds__(256, 3) void out_gemm(
    const unsigned short* __restrict__ Oh, const unsigned short* __restrict__ Wob,
    const float* __restrict__ bo, float* __restrict__ out)
{
    __shared__ unsigned short As[128 * 64];
    __shared__ unsigned short Bs[128 * 64];

    const int tid = threadIdx.x, lane = tid & 63, w = tid >> 6;
    const int wm = (w & 1) * 64, wn = (w >> 1) * 64;
    const int m0 = blockIdx.x * 128, n0 = blockIdx.y * 128;
    const int cn = lane & 15, g = lane >> 4;

    floatx4 acc[4][4];
    #pragma unroll
    for (int i = 0; i < 4; ++i)
        #pragma unroll
        for (int j = 0; j < 4; ++j) acc[i][j] = (floatx4){0.f, 0.f, 0.f, 0.f};

    for (int k0 = 0; k0 < EMB; k0 += 64) {
        __syncthreads();
        #pragma unroll
        for (int p = 0; p < 4; ++p) {
            int u0 = (p * 4 + w) * 64, u = u0 + lane, row = u >> 3, sl = u & 7;
            gld_lds16(Oh  + (size_t)(m0 + row) * EMB + k0 + ((sl ^ (row & 7)) * 8), &As[u0 * 8]);
            gld_lds16(Wob + (size_t)(n0 + row) * EMB + k0 + ((sl ^ (row & 7)) * 8), &Bs[u0 * 8]);
        }
        __syncthreads();
        #pragma unroll
        for (int kc = 0; kc < 2; ++kc) {
            short8 a4[4], b4[4];
            #pragma unroll
            for (int i = 0; i < 4; ++i)
                a4[i] = *(const short8*)&As[(wm + i * 16 + cn) * 64 + (((kc * 4 + g) ^ (cn & 7)) * 8)];
            #pragma unroll
            for (int j = 0; j < 4; ++j)
                b4[j] = *(const short8*)&Bs[(wn + j * 16 + cn) * 64 + (((kc * 4 + g) ^ (cn & 7)) * 8)];
            #pragma unroll
            for (int i = 0; i < 4; ++i)
                #pragma unroll
                for (int j = 0; j < 4; ++j)
                    acc[i][j] = __builtin_amdgcn_mfma_f32_16x16x32_bf16(a4[i], b4[j], acc[i][j], 0, 0, 0);
        }
    }

    #pragma unroll
    for (int j = 0; j < 4; ++j) {
        int col = n0 + wn + j * 16 + cn;
        float bv = bo[col];
        #pragma unroll
        for (int i = 0; i < 4; ++i)
            #pragma unroll
            for (int r = 0; r < 4; ++r)
                out[(size_t)(m0 + wm + i * 16 + g * 4 + r) * EMB + col] = acc[i][j][r] + bv;
    }
}

extern "C" void kernel_launch(void* const* d_in, const int* in_sizes, int n_in,
                              void* d_out, int out_size, void* d_ws, size_t ws_size,
                              hipStream_t stream) {
    const float* q   = (const float*)d_in[0];
    const float* k   = (const float*)d_in[1];
    const float* v   = (const float*)d_in[2];
    const float* ipw = (const float*)d_in[3];
    const float* ipb = (const float*)d_in[4];
    const float* opw = (const float*)d_in[5];
    const float* opb = (const float*)d_in[6];
    float* out = (float*)d_out;

    const size_t HE = (size_t)32 * L_SEQ * HD;           // 4,194,304 shorts
    unsigned short* Qh   = (unsigned short*)d_ws;        // 8 MB
    unsigned short* Kh   = Qh + HE;                      // 8 MB
    unsigned short* Vt   = Kh + HE;                      // 8 MB
    unsigned short* Wipb = Vt + HE;                      // 6 MB
    unsigned short* Wopb = Wipb + (size_t)3 * EMB * EMB; // 2 MB
    unsigned short* Abq  = Wopb + (size_t)EMB * EMB;     // 8 MB
    unsigned short* Abk  = Abq + HE;                     // 8 MB
    unsigned short* Abv  = Abk + HE;                     // 8 MB  (total 56 MB)
    unsigned short* Oh   = Abq;                          // dead after qkv_gemm
    unsigned short* Kf   = Abk;                          // dead after qkv_gemm
    unsigned short* Vf   = Abv;                          // dead after qkv_gemm

    convert_all<<<dim3(16384), 256, 0, stream>>>(q, k, v, ipw, opw, Abq, Abk, Abv, Wipb, Wopb);
    qkv_gemm<<<dim3(32, 24), 256, 0, stream>>>(Abq, Abk, Abv, Wipb, ipb, Qh, Kh, Vt);
    repack_kv<<<dim3(4096), 256, 0, stream>>>(Kh, Vt, Kf, Vf);
    flash_attn_k<<<dim3(32, 32), 256, 0, stream>>>(Qh, Kf, Vf, Oh);
    out_gemm<<<dim3(32, 8), 256, 0, stream>>>(Oh, Wopb, opb, out);
}

// Round 4
// 213.938 us; speedup vs baseline: 1.4401x; 1.0319x over previous
//
#include <hip/hip_runtime.h>
#include <hip/hip_bf16.h>

typedef __attribute__((ext_vector_type(8))) short short8;
typedef __attribute__((ext_vector_type(4))) float floatx4;
typedef __attribute__((ext_vector_type(16))) float floatx16;

#define L_SEQ 2048
#define EMB   1024
#define HD    64
#define QSCALE 0.18033688011112042f   /* 0.125 * log2(e) */
#define FIXMAX2 11.541560327111707f   /* 8 * log2(e) */

__device__ __forceinline__ unsigned short f2bf(float f) {
    unsigned int u = __float_as_uint(f);
    u += 0x7fffu + ((u >> 16) & 1u);   // RNE
    return (unsigned short)(u >> 16);
}
__device__ __forceinline__ unsigned pkbf(float a, float b) {
    return (unsigned)f2bf(a) | ((unsigned)f2bf(b) << 16);
}
__device__ __forceinline__ unsigned pkbf2(float a, float b) {
    __hip_bfloat162 h = __float22bfloat162_rn(make_float2(a, b));
    unsigned u; __builtin_memcpy(&u, &h, 4); return u;
}
__device__ __forceinline__ void gld_lds16(const void* g, void* l) {
    __builtin_amdgcn_global_load_lds(
        (const __attribute__((address_space(1))) unsigned*)g,
        (__attribute__((address_space(3))) unsigned*)l, 16, 0, 0);
}
__device__ __forceinline__ float fexp2(float x) {
    return __builtin_amdgcn_exp2f(x);   // v_exp_f32 (2^x)
}

// ---------- Kernel 0: convert weights + activations fp32 -> bf16 ----------
__global__ __launch_bounds__(256) void convert_all(
    const float* __restrict__ q, const float* __restrict__ k,
    const float* __restrict__ v, const float* __restrict__ ipw,
    const float* __restrict__ opw,
    unsigned short* __restrict__ Abq, unsigned short* __restrict__ Abk,
    unsigned short* __restrict__ Abv, unsigned short* __restrict__ Wipb,
    unsigned short* __restrict__ Wopb)
{
    const int NA = 1048576, NIP = 786432;        // float4 units
    int idx = blockIdx.x * 256 + threadIdx.x;    // 0 .. 4194303
    const float* src; unsigned short* dst; int o;
    if (idx < NA)            { src = q;   dst = Abq;  o = idx; }
    else if (idx < 2 * NA)   { src = k;   dst = Abk;  o = idx - NA; }
    else if (idx < 3 * NA)   { src = v;   dst = Abv;  o = idx - 2 * NA; }
    else if (idx < 3 * NA + NIP) { src = ipw; dst = Wipb; o = idx - 3 * NA; }
    else                     { src = opw; dst = Wopb; o = idx - 3 * NA - NIP; }
    float4 f = ((const float4*)src)[o];
    ((uint2*)dst)[o] = make_uint2(pkbf(f.x, f.y), pkbf(f.z, f.w));
}

// ---------- Kernel 1: QKV projection, all-bf16 (N=3072) ----------
__global__ __launch_bounds__(256, 3) void qkv_gemm(
    const unsigned short* __restrict__ Abq, const unsigned short* __restrict__ Abk,
    const unsigned short* __restrict__ Abv, const unsigned short* __restrict__ Wb,
    const float* __restrict__ Bip,
    unsigned short* __restrict__ Qh, unsigned short* __restrict__ Kh,
    unsigned short* __restrict__ Vt)
{
    __shared__ unsigned short lds[17408];
    unsigned short* As = lds;
    unsigned short* Bs = lds + 8192;

    const int tid = threadIdx.x, lane = tid & 63, w = tid >> 6;
    const int wm = (w & 1) * 64, wn = (w >> 1) * 64;
    const int m0 = blockIdx.x * 128, n0 = blockIdx.y * 128;
    const int cn = lane & 15, g = lane >> 4;
    const int z = n0 >> 10;
    const unsigned short* Ag = (z == 0) ? Abq : (z == 1) ? Abk : Abv;

    floatx4 acc[4][4];
    #pragma unroll
    for (int i = 0; i < 4; ++i)
        #pragma unroll
        for (int j = 0; j < 4; ++j) acc[i][j] = (floatx4){0.f, 0.f, 0.f, 0.f};

    for (int k0 = 0; k0 < EMB; k0 += 64) {
        __syncthreads();
        #pragma unroll
        for (int p = 0; p < 4; ++p) {
            int u0 = (p * 4 + w) * 64, u = u0 + lane, row = u >> 3, sl = u & 7;
            gld_lds16(Ag + (size_t)(m0 + row) * EMB + k0 + ((sl ^ (row & 7)) * 8), &As[u0 * 8]);
            gld_lds16(Wb + (size_t)(n0 + row) * EMB + k0 + ((sl ^ (row & 7)) * 8), &Bs[u0 * 8]);
        }
        __syncthreads();
        #pragma unroll
        for (int kc = 0; kc < 2; ++kc) {
            short8 a4[4], b4[4];
            #pragma unroll
            for (int i = 0; i < 4; ++i)
                a4[i] = *(const short8*)&As[(wm + i * 16 + cn) * 64 + (((kc * 4 + g) ^ (cn & 7)) * 8)];
            #pragma unroll
            for (int j = 0; j < 4; ++j)
                b4[j] = *(const short8*)&Bs[(wn + j * 16 + cn) * 64 + (((kc * 4 + g) ^ (cn & 7)) * 8)];
            #pragma unroll
            for (int i = 0; i < 4; ++i)
                #pragma unroll
                for (int j = 0; j < 4; ++j)
                    acc[i][j] = __builtin_amdgcn_mfma_f32_16x16x32_bf16(a4[i], b4[j], acc[i][j], 0, 0, 0);
        }
    }

    if (z < 2) {
        #pragma unroll
        for (int j = 0; j < 4; ++j) {
            int col = n0 + wn + j * 16 + cn;
            float bv = Bip[col];
            int o = col & 1023, h = o >> 6, d = o & 63;
            #pragma unroll
            for (int i = 0; i < 4; ++i)
                #pragma unroll
                for (int r = 0; r < 4; ++r) {
                    int rr = m0 + wm + i * 16 + g * 4 + r;   // l*2 + b
                    float vv = acc[i][j][r] + bv;
                    int l = rr >> 1, bb = rr & 1, nn = bb * 16 + h;
                    if (z == 0) Qh[((size_t)nn * L_SEQ + l) * HD + d] = f2bf(vv * QSCALE);
                    else        Kh[((size_t)nn * L_SEQ + l) * HD + d] = f2bf(vv);
                }
        }
    } else {
        // z==2: LDS-transposed epilogue -> Vt[n][d][l] coalesced 16B stores
        __syncthreads();
        #pragma unroll
        for (int j = 0; j < 4; ++j) {
            int col_l = wn + j * 16 + cn;
            float bv = Bip[n0 + col_l];
            #pragma unroll
            for (int i = 0; i < 4; ++i) {
                int rrb = wm + i * 16 + g * 4;
                int l0 = rrb >> 1;
                float v0 = acc[i][j][0] + bv, v1 = acc[i][j][1] + bv;
                float v2 = acc[i][j][2] + bv, v3 = acc[i][j][3] + bv;
                *(unsigned*)&lds[col_l * 136 +      l0] = pkbf(v0, v2);
                *(unsigned*)&lds[col_l * 136 + 64 + l0] = pkbf(v1, v3);
            }
        }
        __syncthreads();
        int cl = tid >> 1, bb = tid & 1;
        int o = (n0 - 2048) + cl, h = o >> 6, d = o & 63;
        int nn = bb * 16 + h;
        unsigned short* dst = Vt + ((size_t)nn * HD + d) * L_SEQ + (m0 >> 1);
        const unsigned short* srcp = &lds[cl * 136 + bb * 64];
        #pragma unroll
        for (int i = 0; i < 8; ++i)
            *(uint4*)(dst + i * 8) = *(const uint4*)(srcp + i * 8);
    }
}

// ---------- Kernel 1b: repack K,V into 32-lane MFMA fragment chunks --------
// Kf chunk ck=(n*64+t32)*4+kk : lane l holds Kh[n][t32*32+(l&31)][kk*16+(l>>5)*8 ..+7]
// Vf chunk cv=n*256+kk2*2+dt  : lane l holds Vt[n][dt*32+(l&31)][kk2*16+(l>>5)*8 ..+7]
__global__ __launch_bounds__(256) void repack_kv(
    const unsigned short* __restrict__ Kh, const unsigned short* __restrict__ Vt,
    unsigned short* __restrict__ Kf, unsigned short* __restrict__ Vf)
{
    int Wv = blockIdx.x * 4 + (threadIdx.x >> 6);   // 0..16383
    int lane = threadIdx.x & 63, c32 = lane & 31, hi = lane >> 5;
    if (Wv < 8192) {
        int n = Wv >> 8, rest = Wv & 255, t32 = rest >> 2, kk = rest & 3;
        short8 val = *(const short8*)(Kh + ((size_t)(n * 2048 + t32 * 32 + c32) * 64) + kk * 16 + hi * 8);
        *(short8*)(Kf + (size_t)Wv * 512 + lane * 8) = val;
    } else {
        int cv = Wv - 8192;
        int n = cv >> 8, rest = cv & 255, kk2 = rest >> 1, dt = rest & 1;
        short8 val = *(const short8*)(Vt + ((size_t)(n * 64 + dt * 32 + c32) * 2048) + kk2 * 16 + hi * 8);
        *(short8*)(Vf + (size_t)cv * 512 + lane * 8) = val;
    }
}

// ---------- Kernel 2: flash attention, 32x32 MFMA, in-register softmax ------
// Block = 64 q-rows, 4 waves each owning 512 keys (16 t-iters of 32 keys).
// S^T = K.Q^T via mfma_32x32x16; softmax + P-transpose entirely in registers:
// C-layout col=q=lane&31 means PV's A-fragment only needs a hi-half exchange:
// (w0,w2) = permlane32_swap(pk(p0,p1), pk(p4,p5)) etc.  NO Ps LDS at all ->
// no bank conflicts, no lgkm chain; barrier-free t-loop is compiler-pipelinable.
// l-denominator = fp32 VALU tree (kills the 11% ones-MFMA overhead).
__global__ __launch_bounds__(256, 2) void flash_attn_k(
    const unsigned short* __restrict__ Qh, const unsigned short* __restrict__ Kf,
    const unsigned short* __restrict__ Vf, unsigned short* __restrict__ Oh)
{
    // XCD-aware remap of 1024 blocks: XCD k -> heads [4k,4k+4) (~3MB L2 set).
    const int id = blockIdx.y * 32 + blockIdx.x;
    const int xcd = id & 7, slot = id >> 3;
    const int n = xcd * 4 + (slot & 3);
    const int q0 = (slot >> 2) * 64;

    __shared__ float Uf[2 * 64 * 67];            // combine buffer: 2 regions x 64 lanes x 67

    const int tid = threadIdx.x, lane = tid & 63, w = tid >> 6;
    const int c32 = lane & 31, hi = lane >> 5;

    // Q fragments: B-operand layout: lane holds Q[q0+qt*32+c32][kk*16+hi*8 ..+7]
    short8 qf[2][4];
    #pragma unroll
    for (int qt = 0; qt < 2; ++qt)
        #pragma unroll
        for (int kk = 0; kk < 4; ++kk)
            qf[qt][kk] = *(const short8*)(Qh + ((size_t)n * L_SEQ + q0 + qt * 32 + c32) * HD + kk * 16 + hi * 8);

    floatx16 acc_o[2][2];
    #pragma unroll
    for (int qt = 0; qt < 2; ++qt)
        #pragma unroll
        for (int dt = 0; dt < 2; ++dt)
            #pragma unroll
            for (int r = 0; r < 16; ++r) acc_o[qt][dt][r] = 0.f;
    float lsum0 = 0.f, lsum1 = 0.f;

    const unsigned short* kp = Kf + ((size_t)n * 256 + w * 64) * 512 + lane * 8;
    const unsigned short* vp = Vf + ((size_t)n * 256 + w * 64) * 512 + lane * 8;

    for (int t = 0; t < 16; ++t) {
        // fragment loads: 8 x 1KB coalesced, L2-resident
        short8 kf[4], vf[2][2];
        #pragma unroll
        for (int kk = 0; kk < 4; ++kk)
            kf[kk] = *(const short8*)(kp + kk * 512);
        #pragma unroll
        for (int kc = 0; kc < 2; ++kc)
            #pragma unroll
            for (int dt = 0; dt < 2; ++dt)
                vf[kc][dt] = *(const short8*)(vp + (kc * 2 + dt) * 512);
        kp += 2048; vp += 2048;

        // S^T = K Q^T : 32 keys x 64 q (2 tiles); C: col=q=c32, row=key=(r&3)+8*(r>>2)+4*hi
        floatx16 s[2];
        #pragma unroll
        for (int qt = 0; qt < 2; ++qt) {
            #pragma unroll
            for (int r = 0; r < 16; ++r) s[qt][r] = 0.f;
            __builtin_amdgcn_s_setprio(1);
            #pragma unroll
            for (int kk = 0; kk < 4; ++kk)
                s[qt] = __builtin_amdgcn_mfma_f32_32x32x16_bf16(kf[kk], qf[qt][kk], s[qt], 0, 0, 0);
            __builtin_amdgcn_s_setprio(0);
        }

        #pragma unroll
        for (int qt = 0; qt < 2; ++qt) {
            float p[16];
            #pragma unroll
            for (int r = 0; r < 16; ++r) p[r] = fexp2(s[qt][r] - FIXMAX2);
            float ls = ((p[0] + p[1]) + (p[2] + p[3])) + ((p[4] + p[5]) + (p[6] + p[7]))
                     + ((p[8] + p[9]) + (p[10] + p[11])) + ((p[12] + p[13]) + (p[14] + p[15]));
            if (qt == 0) lsum0 += ls; else lsum1 += ls;

            // pack + hi-half exchange -> PV A-fragments (keys kc*16 + hi*8 ..+7)
            short8 pa[2];
            #pragma unroll
            for (int kc = 0; kc < 2; ++kc) {
                unsigned A = pkbf2(p[kc * 8 + 0], p[kc * 8 + 1]);
                unsigned B = pkbf2(p[kc * 8 + 2], p[kc * 8 + 3]);
                unsigned C = pkbf2(p[kc * 8 + 4], p[kc * 8 + 5]);
                unsigned D = pkbf2(p[kc * 8 + 6], p[kc * 8 + 7]);
                asm("v_permlane32_swap_b32 %0, %1" : "+v"(A), "+v"(C));
                asm("v_permlane32_swap_b32 %0, %1" : "+v"(B), "+v"(D));
                union { unsigned u[4]; short8 v; } cv;
                cv.u[0] = A; cv.u[1] = B; cv.u[2] = C; cv.u[3] = D;
                pa[kc] = cv.v;
            }

            __builtin_amdgcn_s_setprio(1);
            #pragma unroll
            for (int kc = 0; kc < 2; ++kc)
                #pragma unroll
                for (int dt = 0; dt < 2; ++dt)
                    acc_o[qt][dt] = __builtin_amdgcn_mfma_f32_32x32x16_bf16(pa[kc], vf[kc][dt], acc_o[qt][dt], 0, 0, 0);
            __builtin_amdgcn_s_setprio(0);
        }
    }

    // fold hi-halves of lsum: column totals on all lanes
    {
        float a0 = lsum0, b0 = lsum0;
        asm("v_permlane32_swap_b32 %0, %1" : "+v"(a0), "+v"(b0));
        lsum0 = a0 + b0;
        float a1 = lsum1, b1 = lsum1;
        asm("v_permlane32_swap_b32 %0, %1" : "+v"(a1), "+v"(b1));
        lsum1 = a1 + b1;
    }

    // ---- cross-wave combine (exact sums; stride 67 => conflict-free) ----
#define BLOB_STORE(base) do {                                              \
    _Pragma("unroll")                                                      \
    for (int qt = 0; qt < 2; ++qt)                                         \
        _Pragma("unroll")                                                  \
        for (int dt = 0; dt < 2; ++dt)                                     \
            _Pragma("unroll")                                              \
            for (int r = 0; r < 16; ++r)                                   \
                Uf[(base) + (qt * 2 + dt) * 16 + r] = acc_o[qt][dt][r];    \
    Uf[(base) + 64] = lsum0; Uf[(base) + 65] = lsum1;                      \
} while (0)
#define BLOB_ADD(base) do {                                                \
    _Pragma("unroll")                                                      \
    for (int qt = 0; qt < 2; ++qt)                                         \
        _Pragma("unroll")                                                  \
        for (int dt = 0; dt < 2; ++dt)                                     \
            _Pragma("unroll")                                              \
            for (int r = 0; r < 16; ++r)                                   \
                acc_o[qt][dt][r] += Uf[(base) + (qt * 2 + dt) * 16 + r];   \
    lsum0 += Uf[(base) + 64]; lsum1 += Uf[(base) + 65];                    \
} while (0)

    const int r0 = lane * 67, r1 = 64 * 67 + lane * 67;
    __syncthreads();
    if (w == 1) BLOB_STORE(r0);
    if (w == 3) BLOB_STORE(r1);
    __syncthreads();
    if (w == 0) BLOB_ADD(r0);
    if (w == 2) { BLOB_ADD(r1); BLOB_STORE(r1); }
    __syncthreads();
    if (w == 0) {
        BLOB_ADD(r1);
        // epilogue: per-column inverses live at lane=q; broadcast per-row via bpermute
        float inv0 = 1.0f / lsum0, inv1 = 1.0f / lsum1;
        const int hib = hi * 16;
        const int bb = n >> 4, h = n & 15;
        #pragma unroll
        for (int qt = 0; qt < 2; ++qt) {
            float invq = qt ? inv1 : inv0;
            #pragma unroll
            for (int r = 0; r < 16; ++r) {
                int idx = ((r & 3) + 8 * (r >> 2)) * 4 + hib;
                float invr = __int_as_float(__builtin_amdgcn_ds_bpermute(idx, __float_as_int(invq)));
                int q = q0 + qt * 32 + (r & 3) + 8 * (r >> 2) + hi * 4;
                #pragma unroll
                for (int dt = 0; dt < 2; ++dt) {
                    int e = h * 64 + dt * 32 + c32;
                    Oh[((size_t)q * 2 + bb) * EMB + e] = f2bf(acc_o[qt][dt][r] * invr);
                }
            }
        }
    }
#undef BLOB_STORE
#undef BLOB_ADD
}

// ---------- Kernel 3: output projection (all-bf16) ----------
__global__ __launch_bounds__(256, 3) void out_gemm(
    const unsigned short* __restrict__ Oh, const unsigned short* __restrict__ Wob,
    const float* __restrict__ bo, float* __restrict__ out)
{
    __shared__ unsigned short As[128 * 64];
    __shared__ unsigned short Bs[128 * 64];

    const int tid = threadIdx.x, lane = tid & 63, w = tid >> 6;
    const int wm = (w & 1) * 64, wn = (w >> 1) * 64;
    const int m0 = blockIdx.x * 128, n0 = blockIdx.y * 128;
    const int cn = lane & 15, g = lane >> 4;

    floatx4 acc[4][4];
    #pragma unroll
    for (int i = 0; i < 4; ++i)
        #pragma unroll
        for (int j = 0; j < 4; ++j) acc[i][j] = (floatx4){0.f, 0.f, 0.f, 0.f};

    for (int k0 = 0; k0 < EMB; k0 += 64) {
        __syncthreads();
        #pragma unroll
        for (int p = 0; p < 4; ++p) {
            int u0 = (p * 4 + w) * 64, u = u0 + lane, row = u >> 3, sl = u & 7;
            gld_lds16(Oh  + (size_t)(m0 + row) * EMB + k0 + ((sl ^ (row & 7)) * 8), &As[u0 * 8]);
            gld_lds16(Wob + (size_t)(n0 + row) * EMB + k0 + ((sl ^ (row & 7)) * 8), &Bs[u0 * 8]);
        }
        __syncthreads();
        #pragma unroll
        for (int kc = 0; kc < 2; ++kc) {
            short8 a4[4], b4[4];
            #pragma unroll
            for (int i = 0; i < 4; ++i)
                a4[i] = *(const short8*)&As[(wm + i * 16 + cn) * 64 + (((kc * 4 + g) ^ (cn & 7)) * 8)];
            #pragma unroll
            for (int j = 0; j < 4; ++j)
                b4[j] = *(const short8*)&Bs[(wn + j * 16 + cn) * 64 + (((kc * 4 + g) ^ (cn & 7)) * 8)];
            #pragma unroll
            for (int i = 0; i < 4; ++i)
                #pragma unroll
                for (int j = 0; j < 4; ++j)
                    acc[i][j] = __builtin_amdgcn_mfma_f32_16x16x32_bf16(a4[i], b4[j], acc[i][j], 0, 0, 0);
        }
    }

    #pragma unroll
    for (int j = 0; j < 4; ++j) {
        int col = n0 + wn + j * 16 + cn;
        float bv = bo[col];
        #pragma unroll
        for (int i = 0; i < 4; ++i)
            #pragma unroll
            for (int r = 0; r < 4; ++r)
                out[(size_t)(m0 + wm + i * 16 + g * 4 + r) * EMB + col] = acc[i][j][r] + bv;
    }
}

extern "C" void kernel_launch(void* const* d_in, const int* in_sizes, int n_in,
                              void* d_out, int out_size, void* d_ws, size_t ws_size,
                              hipStream_t stream) {
    const float* q   = (const float*)d_in[0];
    const float* k   = (const float*)d_in[1];
    const float* v   = (const float*)d_in[2];
    const float* ipw = (const float*)d_in[3];
    const float* ipb = (const float*)d_in[4];
    const float* opw = (const float*)d_in[5];
    const float* opb = (const float*)d_in[6];
    float* out = (float*)d_out;

    const size_t HE = (size_t)32 * L_SEQ * HD;           // 4,194,304 shorts
    unsigned short* Qh   = (unsigned short*)d_ws;        // 8 MB
    unsigned short* Kh   = Qh + HE;                      // 8 MB
    unsigned short* Vt   = Kh + HE;                      // 8 MB
    unsigned short* Wipb = Vt + HE;                      // 6 MB
    unsigned short* Wopb = Wipb + (size_t)3 * EMB * EMB; // 2 MB
    unsigned short* Abq  = Wopb + (size_t)EMB * EMB;     // 8 MB
    unsigned short* Abk  = Abq + HE;                     // 8 MB
    unsigned short* Abv  = Abk + HE;                     // 8 MB  (total 56 MB)
    unsigned short* Oh   = Abq;                          // dead after qkv_gemm
    unsigned short* Kf   = Abk;                          // dead after qkv_gemm
    unsigned short* Vf   = Abv;                          // dead after qkv_gemm

    convert_all<<<dim3(16384), 256, 0, stream>>>(q, k, v, ipw, opw, Abq, Abk, Abv, Wipb, Wopb);
    qkv_gemm<<<dim3(32, 24), 256, 0, stream>>>(Abq, Abk, Abv, Wipb, ipb, Qh, Kh, Vt);
    repack_kv<<<dim3(4096), 256, 0, stream>>>(Kh, Vt, Kf, Vf);
    flash_attn_k<<<dim3(32, 32), 256, 0, stream>>>(Qh, Kf, Vf, Oh);
    out_gemm<<<dim3(32, 8), 256, 0, stream>>>(Oh, Wopb, opb, out);
}

// Round 5
// 210.679 us; speedup vs baseline: 1.4624x; 1.0155x over previous
//
#include <hip/hip_runtime.h>
#include <hip/hip_bf16.h>

typedef __attribute__((ext_vector_type(8))) short short8;
typedef __attribute__((ext_vector_type(4))) float floatx4;
typedef __attribute__((ext_vector_type(16))) float floatx16;

#define L_SEQ 2048
#define EMB   1024
#define HD    64
#define QSCALE 0.18033688011112042f   /* 0.125 * log2(e) */
#define FIXMAX2 11.541560327111707f   /* 8 * log2(e) */

__device__ __forceinline__ unsigned short f2bf(float f) {
    unsigned int u = __float_as_uint(f);
    u += 0x7fffu + ((u >> 16) & 1u);   // RNE
    return (unsigned short)(u >> 16);
}
__device__ __forceinline__ unsigned pkbf(float a, float b) {
    return (unsigned)f2bf(a) | ((unsigned)f2bf(b) << 16);
}
__device__ __forceinline__ unsigned pkbf2(float a, float b) {
    __hip_bfloat162 h = __float22bfloat162_rn(make_float2(a, b));
    unsigned u; __builtin_memcpy(&u, &h, 4); return u;
}
__device__ __forceinline__ void gld_lds16(const void* g, void* l) {
    __builtin_amdgcn_global_load_lds(
        (const __attribute__((address_space(1))) unsigned*)g,
        (__attribute__((address_space(3))) unsigned*)l, 16, 0, 0);
}
__device__ __forceinline__ float fexp2(float x) {
    return __builtin_amdgcn_exp2f(x);   // v_exp_f32 (2^x)
}

// ---------- Kernel 0: convert weights + activations fp32 -> bf16 ----------
__global__ __launch_bounds__(256) void convert_all(
    const float* __restrict__ q, const float* __restrict__ k,
    const float* __restrict__ v, const float* __restrict__ ipw,
    const float* __restrict__ opw,
    unsigned short* __restrict__ Abq, unsigned short* __restrict__ Abk,
    unsigned short* __restrict__ Abv, unsigned short* __restrict__ Wipb,
    unsigned short* __restrict__ Wopb)
{
    const int NA = 1048576, NIP = 786432;        // float4 units
    int idx = blockIdx.x * 256 + threadIdx.x;    // 0 .. 4194303
    const float* src; unsigned short* dst; int o;
    if (idx < NA)            { src = q;   dst = Abq;  o = idx; }
    else if (idx < 2 * NA)   { src = k;   dst = Abk;  o = idx - NA; }
    else if (idx < 3 * NA)   { src = v;   dst = Abv;  o = idx - 2 * NA; }
    else if (idx < 3 * NA + NIP) { src = ipw; dst = Wipb; o = idx - 3 * NA; }
    else                     { src = opw; dst = Wopb; o = idx - 3 * NA - NIP; }
    float4 f = ((const float4*)src)[o];
    ((uint2*)dst)[o] = make_uint2(pkbf(f.x, f.y), pkbf(f.z, f.w));
}

// ---------- Kernel 1: QKV projection + FUSED fragment repack ----------------
// z==0: Qh[n][l][d] scalar stores (flash reads 32-row fragments, fine).
// z==1: K staged in LDS as [rr(128)][col(128)] (stride 136), then written as
//       Kf fragment chunks with fully-coalesced 1KB stores.
// z==2: V staged LDS-transposed [col(128)][key(64)x2b] (stride 136), then
//       written as Vf fragment chunks (replaces old Vt + repack_kv kernel).
// Kf chunk ck=(nn*64+t32)*4+kk : lane l holds K[nn][t32*32+(l&31)][kk*16+(l>>5)*8 ..+7]
// Vf chunk cv=nn*256+kk2*2+dt  : lane l holds V[nn][dt*32+(l&31)][key=kk2*16+(l>>5)*8 ..+7]
__global__ __launch_bounds__(256, 3) void qkv_gemm(
    const unsigned short* __restrict__ Abq, const unsigned short* __restrict__ Abk,
    const unsigned short* __restrict__ Abv, const unsigned short* __restrict__ Wb,
    const float* __restrict__ Bip,
    unsigned short* __restrict__ Qh, unsigned short* __restrict__ Kf,
    unsigned short* __restrict__ Vf)
{
    __shared__ unsigned short lds[17408];
    unsigned short* As = lds;
    unsigned short* Bs = lds + 8192;

    const int tid = threadIdx.x, lane = tid & 63, w = tid >> 6;
    const int wm = (w & 1) * 64, wn = (w >> 1) * 64;
    const int m0 = blockIdx.x * 128, n0 = blockIdx.y * 128;
    const int cn = lane & 15, g = lane >> 4;
    const int z = n0 >> 10;
    const unsigned short* Ag = (z == 0) ? Abq : (z == 1) ? Abk : Abv;

    floatx4 acc[4][4];
    #pragma unroll
    for (int i = 0; i < 4; ++i)
        #pragma unroll
        for (int j = 0; j < 4; ++j) acc[i][j] = (floatx4){0.f, 0.f, 0.f, 0.f};

    for (int k0 = 0; k0 < EMB; k0 += 64) {
        __syncthreads();
        #pragma unroll
        for (int p = 0; p < 4; ++p) {
            int u0 = (p * 4 + w) * 64, u = u0 + lane, row = u >> 3, sl = u & 7;
            gld_lds16(Ag + (size_t)(m0 + row) * EMB + k0 + ((sl ^ (row & 7)) * 8), &As[u0 * 8]);
            gld_lds16(Wb + (size_t)(n0 + row) * EMB + k0 + ((sl ^ (row & 7)) * 8), &Bs[u0 * 8]);
        }
        __syncthreads();
        #pragma unroll
        for (int kc = 0; kc < 2; ++kc) {
            short8 a4[4], b4[4];
            #pragma unroll
            for (int i = 0; i < 4; ++i)
                a4[i] = *(const short8*)&As[(wm + i * 16 + cn) * 64 + (((kc * 4 + g) ^ (cn & 7)) * 8)];
            #pragma unroll
            for (int j = 0; j < 4; ++j)
                b4[j] = *(const short8*)&Bs[(wn + j * 16 + cn) * 64 + (((kc * 4 + g) ^ (cn & 7)) * 8)];
            #pragma unroll
            for (int i = 0; i < 4; ++i)
                #pragma unroll
                for (int j = 0; j < 4; ++j)
                    acc[i][j] = __builtin_amdgcn_mfma_f32_16x16x32_bf16(a4[i], b4[j], acc[i][j], 0, 0, 0);
        }
    }

    if (z == 0) {
        #pragma unroll
        for (int j = 0; j < 4; ++j) {
            int col = n0 + wn + j * 16 + cn;
            float bv = Bip[col];
            int o = col & 1023, h = o >> 6, d = o & 63;
            #pragma unroll
            for (int i = 0; i < 4; ++i)
                #pragma unroll
                for (int r = 0; r < 4; ++r) {
                    int rr = m0 + wm + i * 16 + g * 4 + r;   // l*2 + b
                    float vv = acc[i][j][r] + bv;
                    int l = rr >> 1, bb = rr & 1, nn = bb * 16 + h;
                    Qh[((size_t)nn * L_SEQ + l) * HD + d] = f2bf(vv * QSCALE);
                }
        }
    } else if (z == 1) {
        // ---- K: stage [rr][col] (stride 136), emit Kf fragment chunks ----
        __syncthreads();                 // other waves done reading As/Bs
        #pragma unroll
        for (int j = 0; j < 4; ++j) {
            int cl = wn + j * 16 + cn;
            float bv = Bip[n0 + cl];
            #pragma unroll
            for (int i = 0; i < 4; ++i)
                #pragma unroll
                for (int r = 0; r < 4; ++r) {
                    int rr = wm + i * 16 + g * 4 + r;
                    lds[rr * 136 + cl] = f2bf(acc[i][j][r] + bv);
                }
        }
        __syncthreads();
        // wave w -> nnl=w : b=w>>1, head h0+(w&1); cc: t32l=cc>>2, kk=cc&3
        const int h0 = (n0 - 1024) >> 6;
        const int b = w >> 1, hl = w & 1;
        const int nn = b * 16 + h0 + hl;
        const int c32l = lane & 31, hi5 = lane >> 5;
        #pragma unroll
        for (int cc = 0; cc < 8; ++cc) {
            int t32l = cc >> 2, kk = cc & 3;
            int rr = (t32l * 32 + c32l) * 2 + b;
            int ccol = hl * 64 + kk * 16 + hi5 * 8;
            uint4 val = *(const uint4*)&lds[rr * 136 + ccol];
            int ck = (nn * 64 + (m0 >> 6) + t32l) * 4 + kk;
            *(uint4*)(Kf + (size_t)ck * 512 + lane * 8) = val;
        }
    } else {
        // ---- V: LDS-transposed stage [col][b*64+key] (stride 136) ----
        __syncthreads();
        #pragma unroll
        for (int j = 0; j < 4; ++j) {
            int col_l = wn + j * 16 + cn;
            float bv = Bip[n0 + col_l];
            #pragma unroll
            for (int i = 0; i < 4; ++i) {
                int rrb = wm + i * 16 + g * 4;
                int l0 = rrb >> 1;
                float v0 = acc[i][j][0] + bv, v1 = acc[i][j][1] + bv;
                float v2 = acc[i][j][2] + bv, v3 = acc[i][j][3] + bv;
                *(unsigned*)&lds[col_l * 136 +      l0] = pkbf(v0, v2);
                *(unsigned*)&lds[col_l * 136 + 64 + l0] = pkbf(v1, v3);
            }
        }
        __syncthreads();
        // emit Vf chunks: wave w -> nnl=w; cc: dt=cc>>2, kk2l=cc&3
        const int h0 = (n0 - 2048) >> 6;
        const int b = w >> 1, hl = w & 1;
        const int nn = b * 16 + h0 + hl;
        const int c32l = lane & 31, hi5 = lane >> 5;
        #pragma unroll
        for (int cc = 0; cc < 8; ++cc) {
            int dt = cc >> 2, kk2l = cc & 3;
            int col_l = hl * 64 + dt * 32 + c32l;
            int keyl = kk2l * 16 + hi5 * 8;
            uint4 val = *(const uint4*)&lds[col_l * 136 + b * 64 + keyl];
            int cv = nn * 256 + ((m0 >> 5) + kk2l) * 2 + dt;
            *(uint4*)(Vf + (size_t)cv * 512 + lane * 8) = val;
        }
    }
}

// ---------- Kernel 2: flash attention, 32x32 MFMA, in-register softmax ------
// Block = 64 q-rows, 4 waves each owning 512 keys (16 t-iters of 32 keys).
// S^T = K.Q^T via mfma_32x32x16 with C-init = -FIXMAX2 (subtract folded into
// the accumulator init -> zero VALU cost). Softmax + P-transpose entirely in
// registers via permlane32_swap; no Ps LDS; barrier-free t-loop.
__global__ __launch_bounds__(256, 2) void flash_attn_k(
    const unsigned short* __restrict__ Qh, const unsigned short* __restrict__ Kf,
    const unsigned short* __restrict__ Vf, unsigned short* __restrict__ Oh)
{
    // XCD-aware remap of 1024 blocks: XCD k -> heads [4k,4k+4) (~3MB L2 set).
    const int id = blockIdx.y * 32 + blockIdx.x;
    const int xcd = id & 7, slot = id >> 3;
    const int n = xcd * 4 + (slot & 3);
    const int q0 = (slot >> 2) * 64;

    __shared__ float Uf[2 * 64 * 67];            // combine buffer: 2 regions x 64 lanes x 67

    const int tid = threadIdx.x, lane = tid & 63, w = tid >> 6;
    const int c32 = lane & 31, hi = lane >> 5;

    // Q fragments: B-operand layout: lane holds Q[q0+qt*32+c32][kk*16+hi*8 ..+7]
    short8 qf[2][4];
    #pragma unroll
    for (int qt = 0; qt < 2; ++qt)
        #pragma unroll
        for (int kk = 0; kk < 4; ++kk)
            qf[qt][kk] = *(const short8*)(Qh + ((size_t)n * L_SEQ + q0 + qt * 32 + c32) * HD + kk * 16 + hi * 8);

    floatx16 acc_o[2][2];
    #pragma unroll
    for (int qt = 0; qt < 2; ++qt)
        #pragma unroll
        for (int dt = 0; dt < 2; ++dt)
            #pragma unroll
            for (int r = 0; r < 16; ++r) acc_o[qt][dt][r] = 0.f;
    float lsum0 = 0.f, lsum1 = 0.f;

    const unsigned short* kp = Kf + ((size_t)n * 256 + w * 64) * 512 + lane * 8;
    const unsigned short* vp = Vf + ((size_t)n * 256 + w * 64) * 512 + lane * 8;

    for (int t = 0; t < 16; ++t) {
        // fragment loads: 8 x 1KB coalesced, L2-resident
        short8 kf[4], vf[2][2];
        #pragma unroll
        for (int kk = 0; kk < 4; ++kk)
            kf[kk] = *(const short8*)(kp + kk * 512);
        #pragma unroll
        for (int kc = 0; kc < 2; ++kc)
            #pragma unroll
            for (int dt = 0; dt < 2; ++dt)
                vf[kc][dt] = *(const short8*)(vp + (kc * 2 + dt) * 512);
        kp += 2048; vp += 2048;

        // S^T = K Q^T - FIXMAX2 : C-init carries the subtract for free
        floatx16 s[2];
        #pragma unroll
        for (int qt = 0; qt < 2; ++qt) {
            #pragma unroll
            for (int r = 0; r < 16; ++r) s[qt][r] = -FIXMAX2;
            __builtin_amdgcn_s_setprio(1);
            #pragma unroll
            for (int kk = 0; kk < 4; ++kk)
                s[qt] = __builtin_amdgcn_mfma_f32_32x32x16_bf16(kf[kk], qf[qt][kk], s[qt], 0, 0, 0);
            __builtin_amdgcn_s_setprio(0);
        }

        #pragma unroll
        for (int qt = 0; qt < 2; ++qt) {
            float p[16];
            #pragma unroll
            for (int r = 0; r < 16; ++r) p[r] = fexp2(s[qt][r]);
            float ls = ((p[0] + p[1]) + (p[2] + p[3])) + ((p[4] + p[5]) + (p[6] + p[7]))
                     + ((p[8] + p[9]) + (p[10] + p[11])) + ((p[12] + p[13]) + (p[14] + p[15]));
            if (qt == 0) lsum0 += ls; else lsum1 += ls;

            // pack + hi-half exchange -> PV A-fragments (keys kc*16 + hi*8 ..+7)
            short8 pa[2];
            #pragma unroll
            for (int kc = 0; kc < 2; ++kc) {
                unsigned A = pkbf2(p[kc * 8 + 0], p[kc * 8 + 1]);
                unsigned B = pkbf2(p[kc * 8 + 2], p[kc * 8 + 3]);
                unsigned C = pkbf2(p[kc * 8 + 4], p[kc * 8 + 5]);
                unsigned D = pkbf2(p[kc * 8 + 6], p[kc * 8 + 7]);
                asm("v_permlane32_swap_b32 %0, %1" : "+v"(A), "+v"(C));
                asm("v_permlane32_swap_b32 %0, %1" : "+v"(B), "+v"(D));
                union { unsigned u[4]; short8 v; } cv;
                cv.u[0] = A; cv.u[1] = B; cv.u[2] = C; cv.u[3] = D;
                pa[kc] = cv.v;
            }

            __builtin_amdgcn_s_setprio(1);
            #pragma unroll
            for (int kc = 0; kc < 2; ++kc)
                #pragma unroll
                for (int dt = 0; dt < 2; ++dt)
                    acc_o[qt][dt] = __builtin_amdgcn_mfma_f32_32x32x16_bf16(pa[kc], vf[kc][dt], acc_o[qt][dt], 0, 0, 0);
            __builtin_amdgcn_s_setprio(0);
        }
    }

    // fold hi-halves of lsum: column totals on all lanes
    {
        float a0 = lsum0, b0 = lsum0;
        asm("v_permlane32_swap_b32 %0, %1" : "+v"(a0), "+v"(b0));
        lsum0 = a0 + b0;
        float a1 = lsum1, b1 = lsum1;
        asm("v_permlane32_swap_b32 %0, %1" : "+v"(a1), "+v"(b1));
        lsum1 = a1 + b1;
    }

    // ---- cross-wave combine (exact sums; stride 67 => conflict-free) ----
#define BLOB_STORE(base) do {                                              \
    _Pragma("unroll")                                                      \
    for (int qt = 0; qt < 2; ++qt)                                         \
        _Pragma("unroll")                                                  \
        for (int dt = 0; dt < 2; ++dt)                                     \
            _Pragma("unroll")                                              \
            for (int r = 0; r < 16; ++r)                                   \
                Uf[(base) + (qt * 2 + dt) * 16 + r] = acc_o[qt][dt][r];    \
    Uf[(base) + 64] = lsum0; Uf[(base) + 65] = lsum1;                      \
} while (0)
#define BLOB_ADD(base) do {                                                \
    _Pragma("unroll")                                                      \
    for (int qt = 0; qt < 2; ++qt)                                         \
        _Pragma("unroll")                                                  \
        for (int dt = 0; dt < 2; ++dt)                                     \
            _Pragma("unroll")                                              \
            for (int r = 0; r < 16; ++r)                                   \
                acc_o[qt][dt][r] += Uf[(base) + (qt * 2 + dt) * 16 + r];   \
    lsum0 += Uf[(base) + 64]; lsum1 += Uf[(base) + 65];                    \
} while (0)

    const int r0 = lane * 67, r1 = 64 * 67 + lane * 67;
    __syncthreads();
    if (w == 1) BLOB_STORE(r0);
    if (w == 3) BLOB_STORE(r1);
    __syncthreads();
    if (w == 0) BLOB_ADD(r0);
    if (w == 2) { BLOB_ADD(r1); BLOB_STORE(r1); }
    __syncthreads();
    if (w == 0) {
        BLOB_ADD(r1);
        // epilogue: per-column inverses live at lane=q; broadcast per-row via bpermute
        float inv0 = 1.0f / lsum0, inv1 = 1.0f / lsum1;
        const int hib = hi * 16;
        const int bb = n >> 4, h = n & 15;
        #pragma unroll
        for (int qt = 0; qt < 2; ++qt) {
            float invq = qt ? inv1 : inv0;
            #pragma unroll
            for (int r = 0; r < 16; ++r) {
                int idx = ((r & 3) + 8 * (r >> 2)) * 4 + hib;
                float invr = __int_as_float(__builtin_amdgcn_ds_bpermute(idx, __float_as_int(invq)));
                int q = q0 + qt * 32 + (r & 3) + 8 * (r >> 2) + hi * 4;
                #pragma unroll
                for (int dt = 0; dt < 2; ++dt) {
                    int e = h * 64 + dt * 32 + c32;
                    Oh[((size_t)q * 2 + bb) * EMB + e] = f2bf(acc_o[qt][dt][r] * invr);
                }
            }
        }
    }
#undef BLOB_STORE
#undef BLOB_ADD
}

// ---------- Kernel 3: output projection (all-bf16) ----------
__global__ __launch_bounds__(256, 3) void out_gemm(
    const unsigned short* __restrict__ Oh, const unsigned short* __restrict__ Wob,
    const float* __restrict__ bo, float* __restrict__ out)
{
    __shared__ unsigned short As[128 * 64];
    __shared__ unsigned short Bs[128 * 64];

    const int tid = threadIdx.x, lane = tid & 63, w = tid >> 6;
    const int wm = (w & 1) * 64, wn = (w >> 1) * 64;
    const int m0 = blockIdx.x * 128, n0 = blockIdx.y * 128;
    const int cn = lane & 15, g = lane >> 4;

    floatx4 acc[4][4];
    #pragma unroll
    for (int i = 0; i < 4; ++i)
        #pragma unroll
        for (int j = 0; j < 4; ++j) acc[i][j] = (floatx4){0.f, 0.f, 0.f, 0.f};

    for (int k0 = 0; k0 < EMB; k0 += 64) {
        __syncthreads();
        #pragma unroll
        for (int p = 0; p < 4; ++p) {
            int u0 = (p * 4 + w) * 64, u = u0 + lane, row = u >> 3, sl = u & 7;
            gld_lds16(Oh  + (size_t)(m0 + row) * EMB + k0 + ((sl ^ (row & 7)) * 8), &As[u0 * 8]);
            gld_lds16(Wob + (size_t)(n0 + row) * EMB + k0 + ((sl ^ (row & 7)) * 8), &Bs[u0 * 8]);
        }
        __syncthreads();
        #pragma unroll
        for (int kc = 0; kc < 2; ++kc) {
            short8 a4[4], b4[4];
            #pragma unroll
            for (int i = 0; i < 4; ++i)
                a4[i] = *(const short8*)&As[(wm + i * 16 + cn) * 64 + (((kc * 4 + g) ^ (cn & 7)) * 8)];
            #pragma unroll
            for (int j = 0; j < 4; ++j)
                b4[j] = *(const short8*)&Bs[(wn + j * 16 + cn) * 64 + (((kc * 4 + g) ^ (cn & 7)) * 8)];
            #pragma unroll
            for (int i = 0; i < 4; ++i)
                #pragma unroll
                for (int j = 0; j < 4; ++j)
                    acc[i][j] = __builtin_amdgcn_mfma_f32_16x16x32_bf16(a4[i], b4[j], acc[i][j], 0, 0, 0);
        }
    }

    #pragma unroll
    for (int j = 0; j < 4; ++j) {
        int col = n0 + wn + j * 16 + cn;
        float bv = bo[col];
        #pragma unroll
        for (int i = 0; i < 4; ++i)
            #pragma unroll
            for (int r = 0; r < 4; ++r)
                out[(size_t)(m0 + wm + i * 16 + g * 4 + r) * EMB + col] = acc[i][j][r] + bv;
    }
}

extern "C" void kernel_launch(void* const* d_in, const int* in_sizes, int n_in,
                              void* d_out, int out_size, void* d_ws, size_t ws_size,
                              hipStream_t stream) {
    const float* q   = (const float*)d_in[0];
    const float* k   = (const float*)d_in[1];
    const float* v   = (const float*)d_in[2];
    const float* ipw = (const float*)d_in[3];
    const float* ipb = (const float*)d_in[4];
    const float* opw = (const float*)d_in[5];
    const float* opb = (const float*)d_in[6];
    float* out = (float*)d_out;

    const size_t HE = (size_t)32 * L_SEQ * HD;           // 4,194,304 shorts
    unsigned short* Qh   = (unsigned short*)d_ws;        // 8 MB
    unsigned short* Kf   = Qh + HE;                      // 8 MB (fragment chunks)
    unsigned short* Vf   = Kf + HE;                      // 8 MB (fragment chunks)
    unsigned short* Wipb = Vf + HE;                      // 6 MB
    unsigned short* Wopb = Wipb + (size_t)3 * EMB * EMB; // 2 MB
    unsigned short* Abq  = Wopb + (size_t)EMB * EMB;     // 8 MB
    unsigned short* Abk  = Abq + HE;                     // 8 MB
    unsigned short* Abv  = Abk + HE;                     // 8 MB  (total 56 MB)
    unsigned short* Oh   = Abq;                          // dead after qkv_gemm

    convert_all<<<dim3(16384), 256, 0, stream>>>(q, k, v, ipw, opw, Abq, Abk, Abv, Wipb, Wopb);
    qkv_gemm<<<dim3(32, 24), 256, 0, stream>>>(Abq, Abk, Abv, Wipb, ipb, Qh, Kf, Vf);
    flash_attn_k<<<dim3(32, 32), 256, 0, stream>>>(Qh, Kf, Vf, Oh);
    out_gemm<<<dim3(32, 8), 256, 0, stream>>>(Oh, Wopb, opb, out);
}

// Round 6
// 207.199 us; speedup vs baseline: 1.4870x; 1.0168x over previous
//
#include <hip/hip_runtime.h>
#include <hip/hip_bf16.h>

typedef __attribute__((ext_vector_type(8))) short short8;
typedef __attribute__((ext_vector_type(4))) float floatx4;
typedef __attribute__((ext_vector_type(16))) float floatx16;

#define L_SEQ 2048
#define EMB   1024
#define HD    64
#define QSCALE 0.18033688011112042f   /* 0.125 * log2(e) */
#define FIXMAX2 11.541560327111707f   /* 8 * log2(e) */

__device__ __forceinline__ unsigned short f2bf(float f) {
    unsigned int u = __float_as_uint(f);
    u += 0x7fffu + ((u >> 16) & 1u);   // RNE
    return (unsigned short)(u >> 16);
}
__device__ __forceinline__ unsigned pkbf(float a, float b) {
    return (unsigned)f2bf(a) | ((unsigned)f2bf(b) << 16);
}
__device__ __forceinline__ unsigned pkbf2(float a, float b) {
    __hip_bfloat162 h = __float22bfloat162_rn(make_float2(a, b));
    unsigned u; __builtin_memcpy(&u, &h, 4); return u;
}
__device__ __forceinline__ void gld_lds16(const void* g, void* l) {
    __builtin_amdgcn_global_load_lds(
        (const __attribute__((address_space(1))) unsigned*)g,
        (__attribute__((address_space(3))) unsigned*)l, 16, 0, 0);
}
__device__ __forceinline__ float fexp2(float x) {
    return __builtin_amdgcn_exp2f(x);   // v_exp_f32 (2^x)
}

// ---------- Kernel 0: convert weights + activations fp32 -> bf16 ----------
__global__ __launch_bounds__(256) void convert_all(
    const float* __restrict__ q, const float* __restrict__ k,
    const float* __restrict__ v, const float* __restrict__ ipw,
    const float* __restrict__ opw,
    unsigned short* __restrict__ Abq, unsigned short* __restrict__ Abk,
    unsigned short* __restrict__ Abv, unsigned short* __restrict__ Wipb,
    unsigned short* __restrict__ Wopb)
{
    const int NA = 1048576, NIP = 786432;        // float4 units
    int idx = blockIdx.x * 256 + threadIdx.x;    // 0 .. 4194303
    const float* src; unsigned short* dst; int o;
    if (idx < NA)            { src = q;   dst = Abq;  o = idx; }
    else if (idx < 2 * NA)   { src = k;   dst = Abk;  o = idx - NA; }
    else if (idx < 3 * NA)   { src = v;   dst = Abv;  o = idx - 2 * NA; }
    else if (idx < 3 * NA + NIP) { src = ipw; dst = Wipb; o = idx - 3 * NA; }
    else                     { src = opw; dst = Wopb; o = idx - 3 * NA - NIP; }
    float4 f = ((const float4*)src)[o];
    ((uint2*)dst)[o] = make_uint2(pkbf(f.x, f.y), pkbf(f.z, f.w));
}

// ---------- Kernel 1: QKV projection + FUSED fragment repack ----------------
// ALL THREE outputs now emitted as MFMA-fragment chunks with coalesced 1KB
// stores (z==0 Q added this round; mirrors the verified z==1 K path, with
// QSCALE folded):
// Qf chunk cq=(nn*64+qt32)*4+kk : lane l holds Q[nn][qt32*32+(l&31)][kk*16+(l>>5)*8 ..+7]
// Kf chunk ck=(nn*64+t32)*4+kk  : lane l holds K[nn][t32*32+(l&31)][kk*16+(l>>5)*8 ..+7]
// Vf chunk cv=nn*256+kk2*2+dt   : lane l holds V[nn][dt*32+(l&31)][key=kk2*16+(l>>5)*8 ..+7]
__global__ __launch_bounds__(256, 3) void qkv_gemm(
    const unsigned short* __restrict__ Abq, const unsigned short* __restrict__ Abk,
    const unsigned short* __restrict__ Abv, const unsigned short* __restrict__ Wb,
    const float* __restrict__ Bip,
    unsigned short* __restrict__ Qf, unsigned short* __restrict__ Kf,
    unsigned short* __restrict__ Vf)
{
    __shared__ unsigned short lds[17408];
    unsigned short* As = lds;
    unsigned short* Bs = lds + 8192;

    const int tid = threadIdx.x, lane = tid & 63, w = tid >> 6;
    const int wm = (w & 1) * 64, wn = (w >> 1) * 64;
    const int m0 = blockIdx.x * 128, n0 = blockIdx.y * 128;
    const int cn = lane & 15, g = lane >> 4;
    const int z = n0 >> 10;
    const unsigned short* Ag = (z == 0) ? Abq : (z == 1) ? Abk : Abv;

    floatx4 acc[4][4];
    #pragma unroll
    for (int i = 0; i < 4; ++i)
        #pragma unroll
        for (int j = 0; j < 4; ++j) acc[i][j] = (floatx4){0.f, 0.f, 0.f, 0.f};

    for (int k0 = 0; k0 < EMB; k0 += 64) {
        __syncthreads();
        #pragma unroll
        for (int p = 0; p < 4; ++p) {
            int u0 = (p * 4 + w) * 64, u = u0 + lane, row = u >> 3, sl = u & 7;
            gld_lds16(Ag + (size_t)(m0 + row) * EMB + k0 + ((sl ^ (row & 7)) * 8), &As[u0 * 8]);
            gld_lds16(Wb + (size_t)(n0 + row) * EMB + k0 + ((sl ^ (row & 7)) * 8), &Bs[u0 * 8]);
        }
        __syncthreads();
        #pragma unroll
        for (int kc = 0; kc < 2; ++kc) {
            short8 a4[4], b4[4];
            #pragma unroll
            for (int i = 0; i < 4; ++i)
                a4[i] = *(const short8*)&As[(wm + i * 16 + cn) * 64 + (((kc * 4 + g) ^ (cn & 7)) * 8)];
            #pragma unroll
            for (int j = 0; j < 4; ++j)
                b4[j] = *(const short8*)&Bs[(wn + j * 16 + cn) * 64 + (((kc * 4 + g) ^ (cn & 7)) * 8)];
            #pragma unroll
            for (int i = 0; i < 4; ++i)
                #pragma unroll
                for (int j = 0; j < 4; ++j)
                    acc[i][j] = __builtin_amdgcn_mfma_f32_16x16x32_bf16(a4[i], b4[j], acc[i][j], 0, 0, 0);
        }
    }

    const int c32l = lane & 31, hi5 = lane >> 5;
    const int b = w >> 1, hl = w & 1;

    if (z < 2) {
        // ---- Q or K: stage [rr][col] (stride 136), emit fragment chunks ----
        __syncthreads();                 // other waves done reading As/Bs
        #pragma unroll
        for (int j = 0; j < 4; ++j) {
            int cl = wn + j * 16 + cn;
            float bv = Bip[n0 + cl];
            #pragma unroll
            for (int i = 0; i < 4; ++i)
                #pragma unroll
                for (int r = 0; r < 4; ++r) {
                    int rr = wm + i * 16 + g * 4 + r;
                    float vv = acc[i][j][r] + bv;
                    lds[rr * 136 + cl] = f2bf(z == 0 ? vv * QSCALE : vv);
                }
        }
        __syncthreads();
        // wave w -> nn; cc: t32l=cc>>2, kk=cc&3
        const int h0 = (n0 & 1023) >> 6;
        const int nn = b * 16 + h0 + hl;
        unsigned short* Dst = (z == 0) ? Qf : Kf;
        #pragma unroll
        for (int cc = 0; cc < 8; ++cc) {
            int t32l = cc >> 2, kk = cc & 3;
            int rr = (t32l * 32 + c32l) * 2 + b;
            int ccol = hl * 64 + kk * 16 + hi5 * 8;
            uint4 val = *(const uint4*)&lds[rr * 136 + ccol];
            int ck = (nn * 64 + (m0 >> 6) + t32l) * 4 + kk;
            *(uint4*)(Dst + (size_t)ck * 512 + lane * 8) = val;
        }
    } else {
        // ---- V: LDS-transposed stage [col][b*64+key] (stride 136) ----
        __syncthreads();
        #pragma unroll
        for (int j = 0; j < 4; ++j) {
            int col_l = wn + j * 16 + cn;
            float bv = Bip[n0 + col_l];
            #pragma unroll
            for (int i = 0; i < 4; ++i) {
                int rrb = wm + i * 16 + g * 4;
                int l0 = rrb >> 1;
                float v0 = acc[i][j][0] + bv, v1 = acc[i][j][1] + bv;
                float v2 = acc[i][j][2] + bv, v3 = acc[i][j][3] + bv;
                *(unsigned*)&lds[col_l * 136 +      l0] = pkbf(v0, v2);
                *(unsigned*)&lds[col_l * 136 + 64 + l0] = pkbf(v1, v3);
            }
        }
        __syncthreads();
        // emit Vf chunks: wave w -> nn; cc: dt=cc>>2, kk2l=cc&3
        const int h0 = (n0 - 2048) >> 6;
        const int nn = b * 16 + h0 + hl;
        #pragma unroll
        for (int cc = 0; cc < 8; ++cc) {
            int dt = cc >> 2, kk2l = cc & 3;
            int col_l = hl * 64 + dt * 32 + c32l;
            int keyl = kk2l * 16 + hi5 * 8;
            uint4 val = *(const uint4*)&lds[col_l * 136 + b * 64 + keyl];
            int cv = nn * 256 + ((m0 >> 5) + kk2l) * 2 + dt;
            *(uint4*)(Vf + (size_t)cv * 512 + lane * 8) = val;
        }
    }
}

// ---------- Kernel 2: flash attention, 32x32 MFMA, in-register softmax ------
// Block = 64 q-rows, 4 waves each owning 512 keys (16 t-iters of 32 keys).
// Q now loaded from Qf fragment chunks (coalesced 1KB, like K/V).
__global__ __launch_bounds__(256, 2) void flash_attn_k(
    const unsigned short* __restrict__ Qf, const unsigned short* __restrict__ Kf,
    const unsigned short* __restrict__ Vf, unsigned short* __restrict__ Oh)
{
    // XCD-aware remap of 1024 blocks: XCD k -> heads [4k,4k+4) (~3MB L2 set).
    const int id = blockIdx.y * 32 + blockIdx.x;
    const int xcd = id & 7, slot = id >> 3;
    const int n = xcd * 4 + (slot & 3);
    const int q0 = (slot >> 2) * 64;

    __shared__ float Uf[2 * 64 * 67];            // combine buffer: 2 regions x 64 lanes x 67

    const int tid = threadIdx.x, lane = tid & 63, w = tid >> 6;
    const int c32 = lane & 31, hi = lane >> 5;

    // Q fragments from Qf chunks: cq = (n*64 + q0/32 + qt)*4 + kk
    short8 qf[2][4];
    #pragma unroll
    for (int qt = 0; qt < 2; ++qt)
        #pragma unroll
        for (int kk = 0; kk < 4; ++kk)
            qf[qt][kk] = *(const short8*)(Qf + ((size_t)((n * 64 + (q0 >> 5) + qt) * 4 + kk)) * 512 + lane * 8);

    floatx16 acc_o[2][2];
    #pragma unroll
    for (int qt = 0; qt < 2; ++qt)
        #pragma unroll
        for (int dt = 0; dt < 2; ++dt)
            #pragma unroll
            for (int r = 0; r < 16; ++r) acc_o[qt][dt][r] = 0.f;
    float lsum0 = 0.f, lsum1 = 0.f;

    const unsigned short* kp = Kf + ((size_t)n * 256 + w * 64) * 512 + lane * 8;
    const unsigned short* vp = Vf + ((size_t)n * 256 + w * 64) * 512 + lane * 8;

    for (int t = 0; t < 16; ++t) {
        // fragment loads: 8 x 1KB coalesced, L2-resident
        short8 kf[4], vf[2][2];
        #pragma unroll
        for (int kk = 0; kk < 4; ++kk)
            kf[kk] = *(const short8*)(kp + kk * 512);
        #pragma unroll
        for (int kc = 0; kc < 2; ++kc)
            #pragma unroll
            for (int dt = 0; dt < 2; ++dt)
                vf[kc][dt] = *(const short8*)(vp + (kc * 2 + dt) * 512);
        kp += 2048; vp += 2048;

        // S^T = K Q^T - FIXMAX2 : C-init carries the subtract for free
        floatx16 s[2];
        #pragma unroll
        for (int qt = 0; qt < 2; ++qt) {
            #pragma unroll
            for (int r = 0; r < 16; ++r) s[qt][r] = -FIXMAX2;
            __builtin_amdgcn_s_setprio(1);
            #pragma unroll
            for (int kk = 0; kk < 4; ++kk)
                s[qt] = __builtin_amdgcn_mfma_f32_32x32x16_bf16(kf[kk], qf[qt][kk], s[qt], 0, 0, 0);
            __builtin_amdgcn_s_setprio(0);
        }

        #pragma unroll
        for (int qt = 0; qt < 2; ++qt) {
            float p[16];
            #pragma unroll
            for (int r = 0; r < 16; ++r) p[r] = fexp2(s[qt][r]);
            float ls = ((p[0] + p[1]) + (p[2] + p[3])) + ((p[4] + p[5]) + (p[6] + p[7]))
                     + ((p[8] + p[9]) + (p[10] + p[11])) + ((p[12] + p[13]) + (p[14] + p[15]));
            if (qt == 0) lsum0 += ls; else lsum1 += ls;

            // pack + hi-half exchange -> PV A-fragments (keys kc*16 + hi*8 ..+7)
            short8 pa[2];
            #pragma unroll
            for (int kc = 0; kc < 2; ++kc) {
                unsigned A = pkbf2(p[kc * 8 + 0], p[kc * 8 + 1]);
                unsigned B = pkbf2(p[kc * 8 + 2], p[kc * 8 + 3]);
                unsigned C = pkbf2(p[kc * 8 + 4], p[kc * 8 + 5]);
                unsigned D = pkbf2(p[kc * 8 + 6], p[kc * 8 + 7]);
                asm("v_permlane32_swap_b32 %0, %1" : "+v"(A), "+v"(C));
                asm("v_permlane32_swap_b32 %0, %1" : "+v"(B), "+v"(D));
                union { unsigned u[4]; short8 v; } cv;
                cv.u[0] = A; cv.u[1] = B; cv.u[2] = C; cv.u[3] = D;
                pa[kc] = cv.v;
            }

            __builtin_amdgcn_s_setprio(1);
            #pragma unroll
            for (int kc = 0; kc < 2; ++kc)
                #pragma unroll
                for (int dt = 0; dt < 2; ++dt)
                    acc_o[qt][dt] = __builtin_amdgcn_mfma_f32_32x32x16_bf16(pa[kc], vf[kc][dt], acc_o[qt][dt], 0, 0, 0);
            __builtin_amdgcn_s_setprio(0);
        }
    }

    // fold hi-halves of lsum: column totals on all lanes
    {
        float a0 = lsum0, b0 = lsum0;
        asm("v_permlane32_swap_b32 %0, %1" : "+v"(a0), "+v"(b0));
        lsum0 = a0 + b0;
        float a1 = lsum1, b1 = lsum1;
        asm("v_permlane32_swap_b32 %0, %1" : "+v"(a1), "+v"(b1));
        lsum1 = a1 + b1;
    }

    // ---- cross-wave combine (exact sums; stride 67 => conflict-free) ----
#define BLOB_STORE(base) do {                                              \
    _Pragma("unroll")                                                      \
    for (int qt = 0; qt < 2; ++qt)                                         \
        _Pragma("unroll")                                                  \
        for (int dt = 0; dt < 2; ++dt)                                     \
            _Pragma("unroll")                                              \
            for (int r = 0; r < 16; ++r)                                   \
                Uf[(base) + (qt * 2 + dt) * 16 + r] = acc_o[qt][dt][r];    \
    Uf[(base) + 64] = lsum0; Uf[(base) + 65] = lsum1;                      \
} while (0)
#define BLOB_ADD(base) do {                                                \
    _Pragma("unroll")                                                      \
    for (int qt = 0; qt < 2; ++qt)                                         \
        _Pragma("unroll")                                                  \
        for (int dt = 0; dt < 2; ++dt)                                     \
            _Pragma("unroll")                                              \
            for (int r = 0; r < 16; ++r)                                   \
                acc_o[qt][dt][r] += Uf[(base) + (qt * 2 + dt) * 16 + r];   \
    lsum0 += Uf[(base) + 64]; lsum1 += Uf[(base) + 65];                    \
} while (0)

    const int r0 = lane * 67, r1 = 64 * 67 + lane * 67;
    __syncthreads();
    if (w == 1) BLOB_STORE(r0);
    if (w == 3) BLOB_STORE(r1);
    __syncthreads();
    if (w == 0) BLOB_ADD(r0);
    if (w == 2) { BLOB_ADD(r1); BLOB_STORE(r1); }
    __syncthreads();
    if (w == 0) {
        BLOB_ADD(r1);
        // epilogue: per-column inverses live at lane=q; broadcast per-row via bpermute
        float inv0 = 1.0f / lsum0, inv1 = 1.0f / lsum1;
        const int hib = hi * 16;
        const int bb = n >> 4, h = n & 15;
        #pragma unroll
        for (int qt = 0; qt < 2; ++qt) {
            float invq = qt ? inv1 : inv0;
            #pragma unroll
            for (int r = 0; r < 16; ++r) {
                int idx = ((r & 3) + 8 * (r >> 2)) * 4 + hib;
                float invr = __int_as_float(__builtin_amdgcn_ds_bpermute(idx, __float_as_int(invq)));
                int q = q0 + qt * 32 + (r & 3) + 8 * (r >> 2) + hi * 4;
                #pragma unroll
                for (int dt = 0; dt < 2; ++dt) {
                    int e = h * 64 + dt * 32 + c32;
                    Oh[((size_t)q * 2 + bb) * EMB + e] = f2bf(acc_o[qt][dt][r] * invr);
                }
            }
        }
    }
#undef BLOB_STORE
#undef BLOB_ADD
}

// ---------- Kernel 3: output projection (all-bf16), 64x128 tiles ------------
// Round-5 defect: 128x128 tiles -> 256 blocks on 256 CUs = 1 block/CU =
// 4 waves/CU (12.5% occupancy), latency-starved like round-0 flash.
// Halve the M-tile: grid (64,8) = 512 blocks -> 2-4 blocks/CU.
__global__ __launch_bounds__(256, 4) void out_gemm(
    const unsigned short* __restrict__ Oh, const unsigned short* __restrict__ Wob,
    const float* __restrict__ bo, float* __restrict__ out)
{
    __shared__ unsigned short As[64 * 64];
    __shared__ unsigned short Bs[128 * 64];

    const int tid = threadIdx.x, lane = tid & 63, w = tid >> 6;
    const int wm = (w & 1) * 32, wn = (w >> 1) * 64;
    const int m0 = blockIdx.x * 64, n0 = blockIdx.y * 128;
    const int cn = lane & 15, g = lane >> 4;

    floatx4 acc[2][4];
    #pragma unroll
    for (int i = 0; i < 2; ++i)
        #pragma unroll
        for (int j = 0; j < 4; ++j) acc[i][j] = (floatx4){0.f, 0.f, 0.f, 0.f};

    for (int k0 = 0; k0 < EMB; k0 += 64) {
        __syncthreads();
        #pragma unroll
        for (int p = 0; p < 4; ++p) {
            int u0 = (p * 4 + w) * 64, u = u0 + lane, row = u >> 3, sl = u & 7;
            if (p < 2)
                gld_lds16(Oh + (size_t)(m0 + row) * EMB + k0 + ((sl ^ (row & 7)) * 8), &As[u0 * 8]);
            gld_lds16(Wob + (size_t)(n0 + row) * EMB + k0 + ((sl ^ (row & 7)) * 8), &Bs[u0 * 8]);
        }
        __syncthreads();
        #pragma unroll
        for (int kc = 0; kc < 2; ++kc) {
            short8 a4[2], b4[4];
            #pragma unroll
            for (int i = 0; i < 2; ++i)
                a4[i] = *(const short8*)&As[(wm + i * 16 + cn) * 64 + (((kc * 4 + g) ^ (cn & 7)) * 8)];
            #pragma unroll
            for (int j = 0; j < 4; ++j)
                b4[j] = *(const short8*)&Bs[(wn + j * 16 + cn) * 64 + (((kc * 4 + g) ^ (cn & 7)) * 8)];
            #pragma unroll
            for (int i = 0; i < 2; ++i)
                #pragma unroll
                for (int j = 0; j < 4; ++j)
                    acc[i][j] = __builtin_amdgcn_mfma_f32_16x16x32_bf16(a4[i], b4[j], acc[i][j], 0, 0, 0);
        }
    }

    #pragma unroll
    for (int j = 0; j < 4; ++j) {
        int col = n0 + wn + j * 16 + cn;
        float bv = bo[col];
        #pragma unroll
        for (int i = 0; i < 2; ++i)
            #pragma unroll
            for (int r = 0; r < 4; ++r)
                out[(size_t)(m0 + wm + i * 16 + g * 4 + r) * EMB + col] = acc[i][j][r] + bv;
    }
}

extern "C" void kernel_launch(void* const* d_in, const int* in_sizes, int n_in,
                              void* d_out, int out_size, void* d_ws, size_t ws_size,
                              hipStream_t stream) {
    const float* q   = (const float*)d_in[0];
    const float* k   = (const float*)d_in[1];
    const float* v   = (const float*)d_in[2];
    const float* ipw = (const float*)d_in[3];
    const float* ipb = (const float*)d_in[4];
    const float* opw = (const float*)d_in[5];
    const float* opb = (const float*)d_in[6];
    float* out = (float*)d_out;

    const size_t HE = (size_t)32 * L_SEQ * HD;           // 4,194,304 shorts
    unsigned short* Qf   = (unsigned short*)d_ws;        // 8 MB (fragment chunks)
    unsigned short* Kf   = Qf + HE;                      // 8 MB (fragment chunks)
    unsigned short* Vf   = Kf + HE;                      // 8 MB (fragment chunks)
    unsigned short* Wipb = Vf + HE;                      // 6 MB
    unsigned short* Wopb = Wipb + (size_t)3 * EMB * EMB; // 2 MB
    unsigned short* Abq  = Wopb + (size_t)EMB * EMB;     // 8 MB
    unsigned short* Abk  = Abq + HE;                     // 8 MB
    unsigned short* Abv  = Abk + HE;                     // 8 MB  (total 56 MB)
    unsigned short* Oh   = Abq;                          // dead after qkv_gemm

    convert_all<<<dim3(16384), 256, 0, stream>>>(q, k, v, ipw, opw, Abq, Abk, Abv, Wipb, Wopb);
    qkv_gemm<<<dim3(32, 24), 256, 0, stream>>>(Abq, Abk, Abv, Wipb, ipb, Qf, Kf, Vf);
    flash_attn_k<<<dim3(32, 32), 256, 0, stream>>>(Qf, Kf, Vf, Oh);
    out_gemm<<<dim3(64, 8), 256, 0, stream>>>(Oh, Wopb, opb, out);
}

// Round 7
// 200.789 us; speedup vs baseline: 1.5344x; 1.0319x over previous
//
#include <hip/hip_runtime.h>
#include <hip/hip_bf16.h>

typedef __attribute__((ext_vector_type(8))) short short8;
typedef __attribute__((ext_vector_type(4))) float floatx4;
typedef __attribute__((ext_vector_type(16))) float floatx16;

#define L_SEQ 2048
#define EMB   1024
#define HD    64
#define QSCALE 0.18033688011112042f   /* 0.125 * log2(e) */
#define FIXMAX2 11.541560327111707f   /* 8 * log2(e) */

__device__ __forceinline__ unsigned short f2bf(float f) {
    unsigned int u = __float_as_uint(f);
    u += 0x7fffu + ((u >> 16) & 1u);   // RNE
    return (unsigned short)(u >> 16);
}
__device__ __forceinline__ unsigned pkbf(float a, float b) {
    return (unsigned)f2bf(a) | ((unsigned)f2bf(b) << 16);
}
__device__ __forceinline__ unsigned pkbf2(float a, float b) {
    __hip_bfloat162 h = __float22bfloat162_rn(make_float2(a, b));
    unsigned u; __builtin_memcpy(&u, &h, 4); return u;
}
__device__ __forceinline__ void gld_lds16(const void* g, void* l) {
    __builtin_amdgcn_global_load_lds(
        (const __attribute__((address_space(1))) unsigned*)g,
        (__attribute__((address_space(3))) unsigned*)l, 16, 0, 0);
}
__device__ __forceinline__ float fexp2(float x) {
    return __builtin_amdgcn_exp2f(x);   // v_exp_f32 (2^x)
}

// ---------- Kernel 0: convert weights + activations fp32 -> bf16 ----------
__global__ __launch_bounds__(256) void convert_all(
    const float* __restrict__ q, const float* __restrict__ k,
    const float* __restrict__ v, const float* __restrict__ ipw,
    const float* __restrict__ opw,
    unsigned short* __restrict__ Abq, unsigned short* __restrict__ Abk,
    unsigned short* __restrict__ Abv, unsigned short* __restrict__ Wipb,
    unsigned short* __restrict__ Wopb)
{
    const int NA = 1048576, NIP = 786432;        // float4 units
    int idx = blockIdx.x * 256 + threadIdx.x;    // 0 .. 4194303
    const float* src; unsigned short* dst; int o;
    if (idx < NA)            { src = q;   dst = Abq;  o = idx; }
    else if (idx < 2 * NA)   { src = k;   dst = Abk;  o = idx - NA; }
    else if (idx < 3 * NA)   { src = v;   dst = Abv;  o = idx - 2 * NA; }
    else if (idx < 3 * NA + NIP) { src = ipw; dst = Wipb; o = idx - 3 * NA; }
    else                     { src = opw; dst = Wopb; o = idx - 3 * NA - NIP; }
    float4 f = ((const float4*)src)[o];
    ((uint2*)dst)[o] = make_uint2(pkbf(f.x, f.y), pkbf(f.z, f.w));
}

// ---------- Kernel 1: QKV projection + FUSED fragment repack ----------------
// Qf chunk cq=(nn*64+qt32)*4+kk : lane l holds Q[nn][qt32*32+(l&31)][kk*16+(l>>5)*8 ..+7]
// Kf chunk ck=(nn*64+t32)*4+kk  : lane l holds K[nn][t32*32+(l&31)][kk*16+(l>>5)*8 ..+7]
// Vf chunk cv=nn*256+kk2*2+dt   : lane l holds V[nn][dt*32+(l&31)][key=kk2*16+(l>>5)*8 ..+7]
__global__ __launch_bounds__(256, 3) void qkv_gemm(
    const unsigned short* __restrict__ Abq, const unsigned short* __restrict__ Abk,
    const unsigned short* __restrict__ Abv, const unsigned short* __restrict__ Wb,
    const float* __restrict__ Bip,
    unsigned short* __restrict__ Qf, unsigned short* __restrict__ Kf,
    unsigned short* __restrict__ Vf)
{
    __shared__ unsigned short lds[17408];
    unsigned short* As = lds;
    unsigned short* Bs = lds + 8192;

    const int tid = threadIdx.x, lane = tid & 63, w = tid >> 6;
    const int wm = (w & 1) * 64, wn = (w >> 1) * 64;
    const int m0 = blockIdx.x * 128, n0 = blockIdx.y * 128;
    const int cn = lane & 15, g = lane >> 4;
    const int z = n0 >> 10;
    const unsigned short* Ag = (z == 0) ? Abq : (z == 1) ? Abk : Abv;

    floatx4 acc[4][4];
    #pragma unroll
    for (int i = 0; i < 4; ++i)
        #pragma unroll
        for (int j = 0; j < 4; ++j) acc[i][j] = (floatx4){0.f, 0.f, 0.f, 0.f};

    for (int k0 = 0; k0 < EMB; k0 += 64) {
        __syncthreads();
        #pragma unroll
        for (int p = 0; p < 4; ++p) {
            int u0 = (p * 4 + w) * 64, u = u0 + lane, row = u >> 3, sl = u & 7;
            gld_lds16(Ag + (size_t)(m0 + row) * EMB + k0 + ((sl ^ (row & 7)) * 8), &As[u0 * 8]);
            gld_lds16(Wb + (size_t)(n0 + row) * EMB + k0 + ((sl ^ (row & 7)) * 8), &Bs[u0 * 8]);
        }
        __syncthreads();
        #pragma unroll
        for (int kc = 0; kc < 2; ++kc) {
            short8 a4[4], b4[4];
            #pragma unroll
            for (int i = 0; i < 4; ++i)
                a4[i] = *(const short8*)&As[(wm + i * 16 + cn) * 64 + (((kc * 4 + g) ^ (cn & 7)) * 8)];
            #pragma unroll
            for (int j = 0; j < 4; ++j)
                b4[j] = *(const short8*)&Bs[(wn + j * 16 + cn) * 64 + (((kc * 4 + g) ^ (cn & 7)) * 8)];
            #pragma unroll
            for (int i = 0; i < 4; ++i)
                #pragma unroll
                for (int j = 0; j < 4; ++j)
                    acc[i][j] = __builtin_amdgcn_mfma_f32_16x16x32_bf16(a4[i], b4[j], acc[i][j], 0, 0, 0);
        }
    }

    const int c32l = lane & 31, hi5 = lane >> 5;
    const int b = w >> 1, hl = w & 1;

    if (z < 2) {
        // ---- Q or K: stage [rr][col] (stride 136), emit fragment chunks ----
        __syncthreads();                 // other waves done reading As/Bs
        #pragma unroll
        for (int j = 0; j < 4; ++j) {
            int cl = wn + j * 16 + cn;
            float bv = Bip[n0 + cl];
            #pragma unroll
            for (int i = 0; i < 4; ++i)
                #pragma unroll
                for (int r = 0; r < 4; ++r) {
                    int rr = wm + i * 16 + g * 4 + r;
                    float vv = acc[i][j][r] + bv;
                    lds[rr * 136 + cl] = f2bf(z == 0 ? vv * QSCALE : vv);
                }
        }
        __syncthreads();
        // wave w -> nn; cc: t32l=cc>>2, kk=cc&3
        const int h0 = (n0 & 1023) >> 6;
        const int nn = b * 16 + h0 + hl;
        unsigned short* Dst = (z == 0) ? Qf : Kf;
        #pragma unroll
        for (int cc = 0; cc < 8; ++cc) {
            int t32l = cc >> 2, kk = cc & 3;
            int rr = (t32l * 32 + c32l) * 2 + b;
            int ccol = hl * 64 + kk * 16 + hi5 * 8;
            uint4 val = *(const uint4*)&lds[rr * 136 + ccol];
            int ck = (nn * 64 + (m0 >> 6) + t32l) * 4 + kk;
            *(uint4*)(Dst + (size_t)ck * 512 + lane * 8) = val;
        }
    } else {
        // ---- V: LDS-transposed stage [col][b*64+key] (stride 136) ----
        __syncthreads();
        #pragma unroll
        for (int j = 0; j < 4; ++j) {
            int col_l = wn + j * 16 + cn;
            float bv = Bip[n0 + col_l];
            #pragma unroll
            for (int i = 0; i < 4; ++i) {
                int rrb = wm + i * 16 + g * 4;
                int l0 = rrb >> 1;
                float v0 = acc[i][j][0] + bv, v1 = acc[i][j][1] + bv;
                float v2 = acc[i][j][2] + bv, v3 = acc[i][j][3] + bv;
                *(unsigned*)&lds[col_l * 136 +      l0] = pkbf(v0, v2);
                *(unsigned*)&lds[col_l * 136 + 64 + l0] = pkbf(v1, v3);
            }
        }
        __syncthreads();
        // emit Vf chunks: wave w -> nn; cc: dt=cc>>2, kk2l=cc&3
        const int h0 = (n0 - 2048) >> 6;
        const int nn = b * 16 + h0 + hl;
        #pragma unroll
        for (int cc = 0; cc < 8; ++cc) {
            int dt = cc >> 2, kk2l = cc & 3;
            int col_l = hl * 64 + dt * 32 + c32l;
            int keyl = kk2l * 16 + hi5 * 8;
            uint4 val = *(const uint4*)&lds[col_l * 136 + b * 64 + keyl];
            int cv = nn * 256 + ((m0 >> 5) + kk2l) * 2 + dt;
            *(uint4*)(Vf + (size_t)cv * 512 + lane * 8) = val;
        }
    }
}

// ---------- Kernel 2: flash attention, 32x32 MFMA, in-register softmax ------
// Block = 64 q-rows, 4 waves each owning 512 keys (16 t-iters of 32 keys).
// NEW this round: explicit 2-deep register pipeline (kfA/vfA <-> kfB/vfB
// ping-pong, statically indexed) so tile t+1's 8 L2 loads are issued before
// tile t's compute -> ~400cy L2 latency hides under S+exp+PV. +32 VGPR, same
// 4 waves/SIMD. Combine shrunk to single-region serial chain (17KB LDS).
__global__ __launch_bounds__(256, 2) void flash_attn_k(
    const unsigned short* __restrict__ Qf, const unsigned short* __restrict__ Kf,
    const unsigned short* __restrict__ Vf, unsigned short* __restrict__ Oh)
{
    // XCD-aware remap of 1024 blocks: XCD k -> heads [4k,4k+4) (~3MB L2 set).
    const int id = blockIdx.y * 32 + blockIdx.x;
    const int xcd = id & 7, slot = id >> 3;
    const int n = xcd * 4 + (slot & 3);
    const int q0 = (slot >> 2) * 64;

    __shared__ float Uf[64 * 67];                // 17152 B single-region combine buf

    const int tid = threadIdx.x, lane = tid & 63, w = tid >> 6;
    const int c32 = lane & 31, hi = lane >> 5;

    // Q fragments from Qf chunks: cq = (n*64 + q0/32 + qt)*4 + kk
    short8 qf[2][4];
    #pragma unroll
    for (int qt = 0; qt < 2; ++qt)
        #pragma unroll
        for (int kk = 0; kk < 4; ++kk)
            qf[qt][kk] = *(const short8*)(Qf + ((size_t)((n * 64 + (q0 >> 5) + qt) * 4 + kk)) * 512 + lane * 8);

    floatx16 acc_o[2][2];
    #pragma unroll
    for (int qt = 0; qt < 2; ++qt)
        #pragma unroll
        for (int dt = 0; dt < 2; ++dt)
            #pragma unroll
            for (int r = 0; r < 16; ++r) acc_o[qt][dt][r] = 0.f;
    float lsum0 = 0.f, lsum1 = 0.f;

    const unsigned short* kbase = Kf + ((size_t)n * 256 + w * 64) * 512 + lane * 8;
    const unsigned short* vbase = Vf + ((size_t)n * 256 + w * 64) * 512 + lane * 8;

#define FLOAD(KF, VF, T) do {                                               \
    const unsigned short* _kp = kbase + (size_t)(T) * 2048;                 \
    const unsigned short* _vp = vbase + (size_t)(T) * 2048;                 \
    _Pragma("unroll")                                                       \
    for (int kk = 0; kk < 4; ++kk)                                          \
        KF[kk] = *(const short8*)(_kp + kk * 512);                          \
    _Pragma("unroll")                                                       \
    for (int kc = 0; kc < 2; ++kc)                                          \
        _Pragma("unroll")                                                   \
        for (int dt = 0; dt < 2; ++dt)                                      \
            VF[kc][dt] = *(const short8*)(_vp + (kc * 2 + dt) * 512);       \
} while (0)

#define FCOMP(KF, VF) do {                                                  \
    floatx16 s_[2];                                                         \
    _Pragma("unroll")                                                       \
    for (int qt = 0; qt < 2; ++qt) {                                        \
        _Pragma("unroll")                                                   \
        for (int r = 0; r < 16; ++r) s_[qt][r] = -FIXMAX2;                  \
        __builtin_amdgcn_s_setprio(1);                                      \
        _Pragma("unroll")                                                   \
        for (int kk = 0; kk < 4; ++kk)                                      \
            s_[qt] = __builtin_amdgcn_mfma_f32_32x32x16_bf16(KF[kk], qf[qt][kk], s_[qt], 0, 0, 0); \
        __builtin_amdgcn_s_setprio(0);                                      \
    }                                                                       \
    _Pragma("unroll")                                                       \
    for (int qt = 0; qt < 2; ++qt) {                                        \
        float p_[16];                                                       \
        _Pragma("unroll")                                                   \
        for (int r = 0; r < 16; ++r) p_[r] = fexp2(s_[qt][r]);              \
        float ls_ = ((p_[0] + p_[1]) + (p_[2] + p_[3])) + ((p_[4] + p_[5]) + (p_[6] + p_[7])) \
                  + ((p_[8] + p_[9]) + (p_[10] + p_[11])) + ((p_[12] + p_[13]) + (p_[14] + p_[15])); \
        if (qt == 0) lsum0 += ls_; else lsum1 += ls_;                       \
        short8 pa_[2];                                                      \
        _Pragma("unroll")                                                   \
        for (int kc = 0; kc < 2; ++kc) {                                    \
            unsigned A_ = pkbf2(p_[kc * 8 + 0], p_[kc * 8 + 1]);            \
            unsigned B_ = pkbf2(p_[kc * 8 + 2], p_[kc * 8 + 3]);            \
            unsigned C_ = pkbf2(p_[kc * 8 + 4], p_[kc * 8 + 5]);            \
            unsigned D_ = pkbf2(p_[kc * 8 + 6], p_[kc * 8 + 7]);            \
            asm("v_permlane32_swap_b32 %0, %1" : "+v"(A_), "+v"(C_));       \
            asm("v_permlane32_swap_b32 %0, %1" : "+v"(B_), "+v"(D_));       \
            union { unsigned u[4]; short8 v; } cv_;                         \
            cv_.u[0] = A_; cv_.u[1] = B_; cv_.u[2] = C_; cv_.u[3] = D_;     \
            pa_[kc] = cv_.v;                                                \
        }                                                                   \
        __builtin_amdgcn_s_setprio(1);                                      \
        _Pragma("unroll")                                                   \
        for (int kc = 0; kc < 2; ++kc)                                      \
            _Pragma("unroll")                                               \
            for (int dt = 0; dt < 2; ++dt)                                  \
                acc_o[qt][dt] = __builtin_amdgcn_mfma_f32_32x32x16_bf16(pa_[kc], VF[kc][dt], acc_o[qt][dt], 0, 0, 0); \
        __builtin_amdgcn_s_setprio(0);                                      \
    }                                                                       \
} while (0)

    short8 kfA[4], vfA[2][2], kfB[4], vfB[2][2];
    FLOAD(kfA, vfA, 0);
    for (int t = 0; t < 16; t += 2) {
        FLOAD(kfB, vfB, t + 1);          // issue t+1 loads before computing t
        FCOMP(kfA, vfA);
        if (t + 2 < 16) FLOAD(kfA, vfA, t + 2);
        FCOMP(kfB, vfB);
    }
#undef FLOAD
#undef FCOMP

    // fold hi-halves of lsum: column totals on all lanes
    {
        float a0 = lsum0, b0 = lsum0;
        asm("v_permlane32_swap_b32 %0, %1" : "+v"(a0), "+v"(b0));
        lsum0 = a0 + b0;
        float a1 = lsum1, b1 = lsum1;
        asm("v_permlane32_swap_b32 %0, %1" : "+v"(a1), "+v"(b1));
        lsum1 = a1 + b1;
    }

    // ---- cross-wave combine: serial chain w3->w2->w1->w0 (exact sums) ----
    // single region, stride 67 dwords => conflict-free; 17KB LDS total.
#define BLOB_STORE() do {                                                  \
    _Pragma("unroll")                                                      \
    for (int qt = 0; qt < 2; ++qt)                                         \
        _Pragma("unroll")                                                  \
        for (int dt = 0; dt < 2; ++dt)                                     \
            _Pragma("unroll")                                              \
            for (int r = 0; r < 16; ++r)                                   \
                Uf[ub + (qt * 2 + dt) * 16 + r] = acc_o[qt][dt][r];        \
    Uf[ub + 64] = lsum0; Uf[ub + 65] = lsum1;                              \
} while (0)
#define BLOB_ADD() do {                                                    \
    _Pragma("unroll")                                                      \
    for (int qt = 0; qt < 2; ++qt)                                         \
        _Pragma("unroll")                                                  \
        for (int dt = 0; dt < 2; ++dt)                                     \
            _Pragma("unroll")                                              \
            for (int r = 0; r < 16; ++r)                                   \
                acc_o[qt][dt][r] += Uf[ub + (qt * 2 + dt) * 16 + r];       \
    lsum0 += Uf[ub + 64]; lsum1 += Uf[ub + 65];                            \
} while (0)

    const int ub = lane * 67;
    __syncthreads();
    if (w == 3) BLOB_STORE();
    __syncthreads();
    if (w == 2) { BLOB_ADD(); BLOB_STORE(); }
    __syncthreads();
    if (w == 1) { BLOB_ADD(); BLOB_STORE(); }
    __syncthreads();
    if (w == 0) {
        BLOB_ADD();
        // epilogue: per-column inverses live at lane=q; broadcast per-row via bpermute
        float inv0 = 1.0f / lsum0, inv1 = 1.0f / lsum1;
        const int hib = hi * 16;
        const int bb = n >> 4, h = n & 15;
        #pragma unroll
        for (int qt = 0; qt < 2; ++qt) {
            float invq = qt ? inv1 : inv0;
            #pragma unroll
            for (int r = 0; r < 16; ++r) {
                int idx = ((r & 3) + 8 * (r >> 2)) * 4 + hib;
                float invr = __int_as_float(__builtin_amdgcn_ds_bpermute(idx, __float_as_int(invq)));
                int q = q0 + qt * 32 + (r & 3) + 8 * (r >> 2) + hi * 4;
                #pragma unroll
                for (int dt = 0; dt < 2; ++dt) {
                    int e = h * 64 + dt * 32 + c32;
                    Oh[((size_t)q * 2 + bb) * EMB + e] = f2bf(acc_o[qt][dt][r] * invr);
                }
            }
        }
    }
#undef BLOB_STORE
#undef BLOB_ADD
}

// ---------- Kernel 3: output projection (all-bf16), 64x128 tiles ------------
__global__ __launch_bounds__(256, 4) void out_gemm(
    const unsigned short* __restrict__ Oh, const unsigned short* __restrict__ Wob,
    const float* __restrict__ bo, float* __restrict__ out)
{
    __shared__ unsigned short As[64 * 64];
    __shared__ unsigned short Bs[128 * 64];

    const int tid = threadIdx.x, lane = tid & 63, w = tid >> 6;
    const int wm = (w & 1) * 32, wn = (w >> 1) * 64;
    const int m0 = blockIdx.x * 64, n0 = blockIdx.y * 128;
    const int cn = lane & 15, g = lane >> 4;

    floatx4 acc[2][4];
    #pragma unroll
    for (int i = 0; i < 2; ++i)
        #pragma unroll
        for (int j = 0; j < 4; ++j) acc[i][j] = (floatx4){0.f, 0.f, 0.f, 0.f};

    for (int k0 = 0; k0 < EMB; k0 += 64) {
        __syncthreads();
        #pragma unroll
        for (int p = 0; p < 4; ++p) {
            int u0 = (p * 4 + w) * 64, u = u0 + lane, row = u >> 3, sl = u & 7;
            if (p < 2)
                gld_lds16(Oh + (size_t)(m0 + row) * EMB + k0 + ((sl ^ (row & 7)) * 8), &As[u0 * 8]);
            gld_lds16(Wob + (size_t)(n0 + row) * EMB + k0 + ((sl ^ (row & 7)) * 8), &Bs[u0 * 8]);
        }
        __syncthreads();
        #pragma unroll
        for (int kc = 0; kc < 2; ++kc) {
            short8 a4[2], b4[4];
            #pragma unroll
            for (int i = 0; i < 2; ++i)
                a4[i] = *(const short8*)&As[(wm + i * 16 + cn) * 64 + (((kc * 4 + g) ^ (cn & 7)) * 8)];
            #pragma unroll
            for (int j = 0; j < 4; ++j)
                b4[j] = *(const short8*)&Bs[(wn + j * 16 + cn) * 64 + (((kc * 4 + g) ^ (cn & 7)) * 8)];
            #pragma unroll
            for (int i = 0; i < 2; ++i)
                #pragma unroll
                for (int j = 0; j < 4; ++j)
                    acc[i][j] = __builtin_amdgcn_mfma_f32_16x16x32_bf16(a4[i], b4[j], acc[i][j], 0, 0, 0);
        }
    }

    #pragma unroll
    for (int j = 0; j < 4; ++j) {
        int col = n0 + wn + j * 16 + cn;
        float bv = bo[col];
        #pragma unroll
        for (int i = 0; i < 2; ++i)
            #pragma unroll
            for (int r = 0; r < 4; ++r)
                out[(size_t)(m0 + wm + i * 16 + g * 4 + r) * EMB + col] = acc[i][j][r] + bv;
    }
}

extern "C" void kernel_launch(void* const* d_in, const int* in_sizes, int n_in,
                              void* d_out, int out_size, void* d_ws, size_t ws_size,
                              hipStream_t stream) {
    const float* q   = (const float*)d_in[0];
    const float* k   = (const float*)d_in[1];
    const float* v   = (const float*)d_in[2];
    const float* ipw = (const float*)d_in[3];
    const float* ipb = (const float*)d_in[4];
    const float* opw = (const float*)d_in[5];
    const float* opb = (const float*)d_in[6];
    float* out = (float*)d_out;

    const size_t HE = (size_t)32 * L_SEQ * HD;           // 4,194,304 shorts
    unsigned short* Qf   = (unsigned short*)d_ws;        // 8 MB (fragment chunks)
    unsigned short* Kf   = Qf + HE;                      // 8 MB (fragment chunks)
    unsigned short* Vf   = Kf + HE;                      // 8 MB (fragment chunks)
    unsigned short* Wipb = Vf + HE;                      // 6 MB
    unsigned short* Wopb = Wipb + (size_t)3 * EMB * EMB; // 2 MB
    unsigned short* Abq  = Wopb + (size_t)EMB * EMB;     // 8 MB
    unsigned short* Abk  = Abq + HE;                     // 8 MB
    unsigned short* Abv  = Abk + HE;                     // 8 MB  (total 56 MB)
    unsigned short* Oh   = Abq;                          // dead after qkv_gemm

    convert_all<<<dim3(16384), 256, 0, stream>>>(q, k, v, ipw, opw, Abq, Abk, Abv, Wipb, Wopb);
    qkv_gemm<<<dim3(32, 24), 256, 0, stream>>>(Abq, Abk, Abv, Wipb, ipb, Qf, Kf, Vf);
    flash_attn_k<<<dim3(32, 32), 256, 0, stream>>>(Qf, Kf, Vf, Oh);
    out_gemm<<<dim3(64, 8), 256, 0, stream>>>(Oh, Wopb, opb, out);
}